// Round 3
// baseline (4645.389 us; speedup 1.0000x reference)
//
#include <hip/hip_runtime.h>
#include <hip/hip_bf16.h>

typedef __hip_bfloat16 bf16;
#define DEV __device__ __forceinline__

static constexpr int T_ = 8, NC = 512, NT = 512, D_ = 256, H_ = 8, NBF = 1419;
static constexpr float EPS_ = 1e-4f;
static constexpr float DN = 0.25f;          // D^-0.25
static constexpr float DIAG_SC = 0.03125f;  // 0.5 * DN^2

DEV float bf2f(unsigned short u) { return __uint_as_float(((unsigned)u) << 16); }
DEV float tofloat(bf16 x) { return __bfloat162float(x); }

// dynamic external-input load: isb ? bf16 : f32
DEV float ldx(const void* p, long i, int isb) {
  if (isb) return bf2f(((const unsigned short*)p)[i]);
  return ((const float*)p)[i];
}
DEV void stx(void* p, long i, float v, int isb) {
  if (isb) ((bf16*)p)[i] = __float2bfloat16(v);
  else     ((float*)p)[i] = v;
}
// unpack 4 packed bf16-pairs (uint4 = 8 bf16) to 8 floats
DEV void unpack8(uint4 u, float* dst) {
  unsigned w[4] = {u.x, u.y, u.z, u.w};
#pragma unroll
  for (int i = 0; i < 4; i++) {
    dst[2 * i + 0] = __uint_as_float((w[i] & 0xffffu) << 16);
    dst[2 * i + 1] = __uint_as_float(w[i] & 0xffff0000u);
  }
}

// ------------------------------------------------------------------
// dtype probe: even-indexed bf16 halves of x_ctx. Genuine bf16 data ->
// sane exponents; fp32 data read as bf16 low-halves -> mantissa noise.
// flag: 1 = external inputs are bf16, 0 = fp32.
// ------------------------------------------------------------------
__global__ __launch_bounds__(256)
void detect_dtype(const void* __restrict__ x, int* __restrict__ flag)
{
  __shared__ int bad;
  if (threadIdx.x == 0) bad = 0;
  __syncthreads();
  int mybad = 0;
  for (int j = 0; j < 16; j++) {
    long i = 2L * (threadIdx.x + 256L * j);
    unsigned short u = ((const unsigned short*)x)[i];
    int e = (u >> 7) & 0xff, mant = u & 0x7f;
    bool b = (e == 0xff) || (e >= 141) || (e <= 93 && !(e == 0 && mant == 0));
    mybad += b ? 1 : 0;
  }
  atomicAdd(&bad, mybad);
  __syncthreads();
  if (threadIdx.x == 0) *flag = (bad > 1024) ? 0 : 1;
}

// ------------------------------------------------------------------
// Generic tiled GEMM: C[M,N] = A[M,K] @ B[K,N] (+bias)(+relu), row-major.
// aMode/cMode: 0=f32, 1=bf16, 2=follow dtFlag. B/bias always follow dtFlag.
// Batched: aOff=(bz/divA)*sA, bOff=(bz%modB)*sB, biasOff=(bz%modB)*sBias,
// cOff=bz*M*N. M,N multiples of 64, K multiple of 16 (true for all calls).
// ------------------------------------------------------------------
__global__ __launch_bounds__(256)
void gemm_k(const void* __restrict__ A, int aMode,
            const void* __restrict__ B, const void* __restrict__ bias,
            void* __restrict__ C, int cMode, int epi,
            const int* __restrict__ dtFlag,
            int M, int N, int K, long sA, int divA, long sB, int modB, long sBias)
{
  __shared__ float As[16][65];
  __shared__ float Bs[16][65];
  const int fl = *dtFlag;
  const int aB = (aMode == 2) ? fl : aMode;
  const int cB = (cMode == 2) ? fl : cMode;
  const int t = threadIdx.x;
  const int bz = blockIdx.z;
  const long aOff = (long)(bz / divA) * sA;
  const long bOff = (long)(bz % modB) * sB;
  const long biasOff = (long)(bz % modB) * sBias;
  const long cOff = (long)bz * M * N;
  const int m0 = blockIdx.y * 64, n0 = blockIdx.x * 64;
  const int tm = t >> 4, tn = t & 15;
  const int am = t >> 2, ak = (t & 3) * 4;
  const int bkr = t >> 4, bn = (t & 15) * 4;
  float acc[4][4] = {};
  for (int k0 = 0; k0 < K; k0 += 16) {
#pragma unroll
    for (int j = 0; j < 4; j++)
      As[ak + j][am] = ldx(A, aOff + (long)(m0 + am) * K + (k0 + ak + j), aB);
#pragma unroll
    for (int j = 0; j < 4; j++)
      Bs[bkr][bn + j] = ldx(B, bOff + (long)(k0 + bkr) * N + (n0 + bn + j), fl);
    __syncthreads();
#pragma unroll
    for (int kk = 0; kk < 16; kk++) {
      float a[4], b[4];
#pragma unroll
      for (int i = 0; i < 4; i++) a[i] = As[kk][tm * 4 + i];
#pragma unroll
      for (int j = 0; j < 4; j++) b[j] = Bs[kk][tn * 4 + j];
#pragma unroll
      for (int i = 0; i < 4; i++)
#pragma unroll
        for (int j = 0; j < 4; j++) acc[i][j] += a[i] * b[j];
    }
    __syncthreads();
  }
#pragma unroll
  for (int i = 0; i < 4; i++) {
    int m = m0 + tm * 4 + i;
#pragma unroll
    for (int j = 0; j < 4; j++) {
      int n = n0 + tn * 4 + j;
      float c = acc[i][j];
      if (epi >= 1) c += ldx(bias, biasOff + n, fl);
      if (epi == 2) c = fmaxf(c, 0.f);
      stx(C, cOff + (long)m * N + n, c, cB);
    }
  }
}

// h1 = relu(h1 + label @ W1[256:259] + b1)
__global__ __launch_bounds__(256)
void fixup_h1(float* __restrict__ h1, const void* __restrict__ label,
              const void* __restrict__ W1, const void* __restrict__ b1,
              const int* __restrict__ dtFlag)
{
  const int fl = *dtFlag;
  int idx = blockIdx.x * 256 + threadIdx.x;
  int m = idx >> 8, n = idx & 255;
  float c = h1[idx] + ldx(b1, n, fl);
#pragma unroll
  for (int j = 0; j < 3; j++)
    c += ldx(label, m * 3 + j, fl) * ldx(W1, (256 + j) * 256 + n, fl);
  h1[idx] = fmaxf(c, 0.f);
}

// diag[r] = 0.5*dn^2 * sum_d X[r,d]^2 ; X bf16, one wave per row
__global__ __launch_bounds__(64)
void diag_kernel(const bf16* __restrict__ X, float* __restrict__ diag)
{
  int r = blockIdx.x, lane = threadIdx.x;
  uint2 u = ((const uint2*)(X + (long)r * 256))[lane];  // 4 bf16
  float a = bf2f((unsigned short)(u.x & 0xffff)), b2 = bf2f((unsigned short)(u.x >> 16));
  float c = bf2f((unsigned short)(u.y & 0xffff)), d = bf2f((unsigned short)(u.y >> 16));
  float s = a * a + b2 * b2 + c * c + d * d;
#pragma unroll
  for (int off = 32; off > 0; off >>= 1) s += __shfl_down(s, off);
  if (lane == 0) diag[r] = DIAG_SC * s;
}

// ------------------------------------------------------------------
// Key-side fused: per (bz=t*H+h, f-tile of 32):
//   ksumE[f] = sum_n exp(dd_nf - diag_n), ctxE[f,e] = sum_n exp(..)*v[n,e],
//   mpart = max over tile of dd.  exp(-mk) applied later as scalar.
// k, v bf16; ctxE bf16 out.
// ------------------------------------------------------------------
__global__ __launch_bounds__(256)
void key_fused(const bf16* __restrict__ k, const bf16* __restrict__ v,
               const void* __restrict__ proj, const float* __restrict__ diagk,
               float* __restrict__ ksumE, bf16* __restrict__ ctxE,
               float* __restrict__ mpart, const int* __restrict__ dtFlag)
{
  constexpr int FT = 32, PS = 258;
  __shared__ bf16 projS[FT * PS];
  __shared__ float kS[16][256];
  __shared__ float vS[16][256];
  __shared__ float pS[16][33];
  __shared__ float red[4];
  const int fl = *dtFlag;
  const int bz = blockIdx.y, ft = blockIdx.x, f0 = ft * FT;
  const int t = threadIdx.x;
  for (int i = t; i < FT * 256; i += 256) {
    int fr = i >> 8, d = i & 255;
    int fg = f0 + fr;
    float pv = (fg < NBF) ? ldx(proj, (long)fg * 256 + d, fl) : 0.f;
    projS[fr * PS + d] = __float2bfloat16(pv);
  }
  const bf16* kb = k + (long)bz * NC * 256;
  const bf16* vb = v + (long)bz * NC * 256;
  const float* db = diagk + bz * NC;
  const int fi = t >> 4, ei = t & 15;
  float acc[2][16] = {};
  float ksum_acc = 0.f;
  float mx = -1e30f;
  const int fli = t & 31;
  const bool fvalid = (f0 + fli) < NBF;

  for (int n0 = 0; n0 < NC; n0 += 16) {
    {
      int nl = t >> 4, d0 = (t & 15) * 16;
      const uint4* kg = (const uint4*)(kb + (long)(n0 + nl) * 256 + d0);
      const uint4* vg = (const uint4*)(vb + (long)(n0 + nl) * 256 + d0);
      unpack8(kg[0], &kS[nl][d0]); unpack8(kg[1], &kS[nl][d0 + 8]);
      unpack8(vg[0], &vS[nl][d0]); unpack8(vg[1], &vS[nl][d0 + 8]);
    }
    __syncthreads();
#pragma unroll
    for (int jj = 0; jj < 2; jj++) {
      int nl = ((t >> 5) << 1) + jj;
      const float* kr = &kS[nl][0];
      const bf16* pr = &projS[fli * PS];
      float dot = 0.f;
#pragma unroll 8
      for (int d = 0; d < 256; d++) dot += kr[d] * tofloat(pr[d]);
      float sc = DN * dot;
      if (fvalid) mx = fmaxf(mx, sc);
      pS[nl][fli] = fvalid ? __expf(fminf(sc - db[n0 + nl], 80.f)) : 0.f;
    }
    __syncthreads();
    if (t < 32 && fvalid) {
#pragma unroll
      for (int n = 0; n < 16; n++) ksum_acc += pS[n][t];
    }
#pragma unroll 2
    for (int n = 0; n < 16; n++) {
      float p0 = pS[n][fi * 2 + 0];
      float p1 = pS[n][fi * 2 + 1];
#pragma unroll
      for (int i = 0; i < 16; i++) {
        float vv = vS[n][ei + 16 * i];
        acc[0][i] += p0 * vv;
        acc[1][i] += p1 * vv;
      }
    }
    __syncthreads();
  }
  if (t < 32 && fvalid) ksumE[(long)bz * NBF + f0 + t] = ksum_acc;
#pragma unroll
  for (int j = 0; j < 2; j++) {
    int f = f0 + fi * 2 + j;
    if (f < NBF) {
      bf16* cg = ctxE + ((long)bz * NBF + f) * 256 + ei;
#pragma unroll
      for (int i = 0; i < 16; i++) cg[16 * i] = __float2bfloat16(acc[j][i]);
    }
  }
#pragma unroll
  for (int off = 32; off > 0; off >>= 1) mx = fmaxf(mx, __shfl_down(mx, off));
  if ((t & 63) == 0) red[t >> 6] = mx;
  __syncthreads();
  if (t == 0)
    mpart[bz * 45 + ft] = fmaxf(fmaxf(red[0], red[1]), fmaxf(red[2], red[3]));
}

__global__ __launch_bounds__(64)
void mk_reduce(const float* __restrict__ mpart, float* __restrict__ mk)
{
  int bz = blockIdx.x, l = threadIdx.x;
  float m = (l < 45) ? mpart[bz * 45 + l] : -1e30f;
#pragma unroll
  for (int off = 32; off > 0; off >>= 1) m = fmaxf(m, __shfl_down(m, off));
  if (l == 0) mk[bz] = m;
}

__global__ __launch_bounds__(256)
void sv_kernel(const bf16* __restrict__ v, float* __restrict__ Sv)
{
  int bz = blockIdx.x, e = threadIdx.x;
  const bf16* vb = v + (long)bz * NC * 256;
  float s = 0.f;
  for (int n = 0; n < NC; n++) s += tofloat(vb[n * 256 + e]);
  Sv[bz * 256 + e] = s;
}

// ctx[f,e] = exp(-mk)*ctxE[f,e] + EPS*Sv[e]   (in place, bf16)
__global__ __launch_bounds__(256)
void ctx_fin(bf16* __restrict__ ctx, const float* __restrict__ Sv,
             const float* __restrict__ mk)
{
  int bz = blockIdx.y, f = blockIdx.x, e = threadIdx.x;
  float emk = __expf(-mk[bz]);
  long idx = ((long)bz * NBF + f) * 256 + e;
  float x = tofloat(ctx[idx]);
  ctx[idx] = __float2bfloat16(emk * x + EPS_ * Sv[bz * 256 + e]);
}

// ksum[f] = exp(-mk)*ksumE[f] + NC*EPS (in place); ksumtot = sum_f
__global__ __launch_bounds__(256)
void ksum_fin(float* __restrict__ ksumE, const float* __restrict__ mk,
              float* __restrict__ ksumtot)
{
  __shared__ float red[4];
  int bz = blockIdx.x, t = threadIdx.x;
  float emk = __expf(-mk[bz]);
  float s = 0.f;
  for (int f = t; f < NBF; f += 256) {
    float kf = emk * ksumE[(long)bz * NBF + f] + (float)NC * EPS_;
    ksumE[(long)bz * NBF + f] = kf;
    s += kf;
  }
#pragma unroll
  for (int off = 32; off > 0; off >>= 1) s += __shfl_down(s, off);
  if ((t & 63) == 0) red[t >> 6] = s;
  __syncthreads();
  if (t == 0) ksumtot[bz] = red[0] + red[1] + red[2] + red[3];
}

__global__ __launch_bounds__(256)
void ctxsum_kernel(const bf16* __restrict__ ctx, float* __restrict__ ctxsum)
{
  int bz = blockIdx.x, e = threadIdx.x;
  float s = 0.f;
  for (int f = 0; f < NBF; f++) s += tofloat(ctx[((long)bz * NBF + f) * 256 + e]);
  ctxsum[bz * 256 + e] = s;
}

// ------------------------------------------------------------------
// Query-side fused. q bf16, ctx bf16, writes merged bf16 [t][n][e*8+h].
// ------------------------------------------------------------------
__global__ __launch_bounds__(256)
void q_fused(const bf16* __restrict__ q, const void* __restrict__ proj,
             const float* __restrict__ diagq, const bf16* __restrict__ ctx,
             const float* __restrict__ ksum, const float* __restrict__ ctxsum,
             const float* __restrict__ ksumtot, bf16* __restrict__ merged,
             const int* __restrict__ dtFlag)
{
  constexpr int FT = 32, PS = 258;
  __shared__ float qS[32 * 256];
  __shared__ bf16 projS[FT * PS];
  __shared__ float eS[32][33];
  __shared__ float ksumS[FT];
  __shared__ float srowS[32], mrowS[32];
  const int fl = *dtFlag;
  const int bz = blockIdx.y, nt = blockIdx.x, t = threadIdx.x;
  const int tq = bz / H_, hh = bz % H_;
  const bf16* qb = q + ((long)bz * NT + nt * 32) * 256;
  for (int i = t; i < 1024; i += 256) {
    uint4 u = ((const uint4*)qb)[i];
    unpack8(u, &qS[8 * i]);
  }
  float accS[4][8] = {};
  float s_acc = 0.f, rmax = 0.f;
  const int ni = t >> 5, ei = t & 31;
  const int fli = t & 31;
  __syncthreads();

  for (int ftile = 0; ftile < 45; ftile++) {
    int f0 = ftile * FT;
    int fcnt = (NBF - f0 < FT) ? (NBF - f0) : FT;
    for (int i = t; i < FT * 256; i += 256) {
      int fr = i >> 8, d = i & 255;
      int fg = f0 + fr;
      float pv = (fg < NBF) ? ldx(proj, (long)fg * 256 + d, fl) : 0.f;
      projS[fr * PS + d] = __float2bfloat16(pv);
    }
    if (t < FT) ksumS[t] = (f0 + t < NBF) ? ksum[(long)bz * NBF + f0 + t] : 0.f;
    __syncthreads();
#pragma unroll
    for (int jj = 0; jj < 4; jj++) {
      int nl = (t >> 5) * 4 + jj;
      const float* qr = &qS[nl * 256];
      const bf16* pr = &projS[fli * PS];
      float dot = 0.f;
#pragma unroll 8
      for (int d = 0; d < 256; d++) dot += qr[d] * tofloat(pr[d]);
      eS[nl][fli] = (f0 + fli < NBF) ? __expf(fminf(DN * dot, 80.f)) : 0.f;
    }
    __syncthreads();
    if (t < 32) {
      for (int f = 0; f < fcnt; f++) {
        float ev = eS[t][f];
        s_acc += ev * ksumS[f];
        rmax = fmaxf(rmax, ev);
      }
    }
    const bf16* cb = ctx + ((long)bz * NBF + f0) * 256 + ei;
    for (int f = 0; f < fcnt; f++) {
      float e0 = eS[ni * 4 + 0][f];
      float e1 = eS[ni * 4 + 1][f];
      float e2 = eS[ni * 4 + 2][f];
      float e3 = eS[ni * 4 + 3][f];
      const bf16* cr = cb + (long)f * 256;
#pragma unroll
      for (int i = 0; i < 8; i++) {
        float cv = tofloat(cr[32 * i]);
        accS[0][i] += e0 * cv;
        accS[1][i] += e1 * cv;
        accS[2][i] += e2 * cv;
        accS[3][i] += e3 * cv;
      }
    }
    __syncthreads();
  }
  if (t < 32) { srowS[t] = s_acc; mrowS[t] = rmax; }
  __syncthreads();
  float ktot = ksumtot[bz];
  const float* csb = ctxsum + bz * 256;
#pragma unroll
  for (int j = 0; j < 4; j++) {
    int nl = ni * 4 + j;
    int ng = nt * 32 + nl;
    float c = __expf(-diagq[(long)bz * NT + ng]) / fmaxf(mrowS[nl], 1e-30f);
    float inv = 1.f / (c * srowS[nl] + EPS_ * ktot);
#pragma unroll
    for (int i = 0; i < 8; i++) {
      int e = ei + 32 * i;
      float num = c * accS[j][i] + EPS_ * csb[e];
      merged[(((long)tq * NT + ng) * 256 + e) * H_ + hh] = __float2bfloat16(num * inv);
    }
  }
}

// ------------------------------------------------------------------
extern "C" void kernel_launch(void* const* d_in, const int* in_sizes, int n_in,
                              void* d_out, int out_size, void* d_ws, size_t ws_size,
                              hipStream_t stream)
{
  const void* x_ctx = d_in[0];
  const void* label = d_in[1];
  const void* x_tgt = d_in[2];
  const void* W1 = d_in[3];
  const void* b1 = d_in[4];
  const void* W2 = d_in[5];
  const void* b2 = d_in[6];
  const void* W3 = d_in[7];
  const void* b3 = d_in[8];
  const void* Wk = d_in[9];
  const void* bk = d_in[10];
  const void* Wv = d_in[11];
  const void* bv = d_in[12];
  const void* Wq = d_in[13];
  const void* bq = d_in[14];
  const void* Wo = d_in[15];
  const void* bo = d_in[16];
  const void* Wmu = d_in[17];
  const void* bmu = d_in[18];
  const void* proj = d_in[19];

  // Arena (floats), peak ~80.8 MB:
  //  F0: kB bf16 (8,388,608 el = 4,194,304 f) -> qB bf16 -> rep fp32 (1M f)
  //  F1: vB bf16 (4,194,304 f) -> merged bf16 (8,388,608 el, same size)
  //  F2: h1,h2,cf fp32 (3M f) -> ctxE bf16 (23,248,896 el = 11,624,448 f)
  //  F3: tail scalars
  float* W = (float*)d_ws;
  const long F0 = 0, F1 = 4194304, F2 = 8388608;
  const long F3 = F2 + 11624448;
  bf16* kB = (bf16*)(W + F0);
  bf16* qB = (bf16*)(W + F0);
  float* rep = W + F0;
  bf16* vB = (bf16*)(W + F1);
  bf16* merged = (bf16*)(W + F1);
  float* h1 = W + F2;
  float* h2 = W + F2 + 1048576;
  float* cf = W + F2 + 2097152;
  bf16* ctxE = (bf16*)(W + F2);
  long o = F3;
  auto alloc = [&](long n) { float* p = W + o; o += n; return p; };
  float* dgk = alloc(32768);
  float* dgq = alloc(32768);
  float* ksumE = alloc((long)64 * NBF);
  float* mpart = alloc(64 * 45);
  float* mk = alloc(64);
  float* Sv = alloc(64 * 256);
  float* ctxs = alloc(64 * 256);
  float* ktot = alloc(64);
  int* dtFlag = (int*)alloc(64);
  (void)ws_size; (void)in_sizes; (void)n_in; (void)out_size;

  const dim3 B(256);
  detect_dtype<<<1, B, 0, stream>>>(x_ctx, dtFlag);
  // 1. task-encoder MLP (R2, dead before ctxE is written)
  gemm_k<<<dim3(4, 64, 1), B, 0, stream>>>(
      x_ctx, 2, W1, nullptr, h1, 0, 0, dtFlag, 4096, 256, 256, 0L, 1, 0L, 1, 0L);
  fixup_h1<<<4096, B, 0, stream>>>(h1, label, W1, b1, dtFlag);
  gemm_k<<<dim3(4, 64, 1), B, 0, stream>>>(
      h1, 0, W2, b2, h2, 0, 2, dtFlag, 4096, 256, 256, 0L, 1, 0L, 1, 0L);
  gemm_k<<<dim3(4, 64, 1), B, 0, stream>>>(
      h2, 0, W3, b3, cf, 0, 2, dtFlag, 4096, 256, 256, 0L, 1, 0L, 1, 0L);
  // 2. k/v projections (batched over t*H), bf16 outputs
  gemm_k<<<dim3(4, 8, 64), B, 0, stream>>>(
      x_ctx, 2, Wk, bk, kB, 1, 1, dtFlag, 512, 256, 256, (long)512 * 256, H_, 65536L, H_, 256L);
  gemm_k<<<dim3(4, 8, 64), B, 0, stream>>>(
      cf, 0, Wv, bv, vB, 1, 1, dtFlag, 512, 256, 256, (long)512 * 256, H_, 65536L, H_, 256L);
  // 3. key diag, key side fused, finalize
  diag_kernel<<<32768, 64, 0, stream>>>(kB, dgk);
  key_fused<<<dim3(45, 64), B, 0, stream>>>(kB, vB, proj, dgk, ksumE, ctxE, mpart, dtFlag);
  mk_reduce<<<64, 64, 0, stream>>>(mpart, mk);
  sv_kernel<<<64, B, 0, stream>>>(vB, Sv);
  ctx_fin<<<dim3(NBF, 64), B, 0, stream>>>(ctxE, Sv, mk);
  ksum_fin<<<64, B, 0, stream>>>(ksumE, mk, ktot);
  ctxsum_kernel<<<64, B, 0, stream>>>(ctxE, ctxs);
  // 4. q projection (over kB region — kB dead), q diag
  gemm_k<<<dim3(4, 8, 64), B, 0, stream>>>(
      x_tgt, 2, Wq, bq, qB, 1, 1, dtFlag, 512, 256, 256, (long)512 * 256, H_, 65536L, H_, 256L);
  diag_kernel<<<32768, 64, 0, stream>>>(qB, dgq);
  // 5. query side fused -> merged bf16 (over vB region — vB dead)
  q_fused<<<dim3(16, 64), B, 0, stream>>>(qB, proj, dgq, ctxE, ksumE, ctxs, ktot, merged, dtFlag);
  // 6. output projections (rep over qB region — qB dead)
  gemm_k<<<dim3(4, 64, 1), B, 0, stream>>>(
      merged, 1, Wo, bo, rep, 0, 1, dtFlag, 4096, 256, 2048, 0L, 1, 0L, 1, 0L);
  gemm_k<<<dim3(4, 64, 1), B, 0, stream>>>(
      rep, 0, Wmu, bmu, d_out, 2, 1, dtFlag, 4096, 256, 256, 0L, 1, 0L, 1, 0L);
}

// Round 6
// 1413.613 us; speedup vs baseline: 3.2862x; 3.2862x over previous
//
#include <hip/hip_runtime.h>
#include <hip/hip_bf16.h>

typedef __hip_bfloat16 bf16;
typedef __attribute__((ext_vector_type(8))) short short8;
typedef __attribute__((ext_vector_type(4))) float f32x4;
typedef __attribute__((ext_vector_type(4))) unsigned short us4;
#define DEV __device__ __forceinline__

static constexpr int T_ = 8, NC = 512, NT = 512, D_ = 256, H_ = 8, NBF = 1419;
static constexpr int FP = 1440;             // padded F (45*32), zero-filled tail
static constexpr float EPS_ = 1e-4f;
static constexpr float DN = 0.25f;          // D^-0.25
static constexpr float DIAG_SC = 0.03125f;  // 0.5 * DN^2

DEV float bf2f(unsigned short u) { return __uint_as_float(((unsigned)u) << 16); }
DEV float tofloat(bf16 x) { return __bfloat162float(x); }
DEV unsigned short f2bu(float x) { bf16 h = __float2bfloat16(x); return *(unsigned short*)&h; }

DEV float ldx(const void* p, long i, int isb) {
  if (isb) return bf2f(((const unsigned short*)p)[i]);
  return ((const float*)p)[i];
}
DEV void stx(void* p, long i, float v, int isb) {
  if (isb) ((bf16*)p)[i] = __float2bfloat16(v);
  else     ((float*)p)[i] = v;
}
DEV void unpack8(uint4 u, float* dst) {
  unsigned w[4] = {u.x, u.y, u.z, u.w};
#pragma unroll
  for (int i = 0; i < 4; i++) {
    dst[2 * i + 0] = __uint_as_float((w[i] & 0xffffu) << 16);
    dst[2 * i + 1] = __uint_as_float(w[i] & 0xffff0000u);
  }
}

// ------------------------------------------------------------------
// dtype probe (1 = bf16 inputs, 0 = fp32)
// ------------------------------------------------------------------
__global__ __launch_bounds__(256)
void detect_dtype(const void* __restrict__ x, int* __restrict__ flag)
{
  __shared__ int bad;
  if (threadIdx.x == 0) bad = 0;
  __syncthreads();
  int mybad = 0;
  for (int j = 0; j < 16; j++) {
    long i = 2L * (threadIdx.x + 256L * j);
    unsigned short u = ((const unsigned short*)x)[i];
    int e = (u >> 7) & 0xff, mant = u & 0x7f;
    bool b = (e == 0xff) || (e >= 141) || (e <= 93 && !(e == 0 && mant == 0));
    mybad += b ? 1 : 0;
  }
  atomicAdd(&bad, mybad);
  __syncthreads();
  if (threadIdx.x == 0) *flag = (bad > 1024) ? 0 : 1;
}

// proj -> bf16 [FP][256], zero rows past NBF
__global__ __launch_bounds__(256)
void conv_proj(const void* __restrict__ proj, bf16* __restrict__ projB,
               const int* __restrict__ dtFlag)
{
  const int fl = *dtFlag;
  int f = blockIdx.x, t = threadIdx.x;
  float v = (f < NBF) ? ldx(proj, (long)f * 256 + t, fl) : 0.f;
  projB[(long)f * 256 + t] = __float2bfloat16(v);
}

// ------------------------------------------------------------------
// Generic tiled GEMM (VALU). bPerm: B row k -> ((k&255)<<3)|(k>>8).
// cT=1: store C transposed at cOff + n*M + m.
// ------------------------------------------------------------------
__global__ __launch_bounds__(256)
void gemm_k(const void* __restrict__ A, int aMode,
            const void* __restrict__ B, const void* __restrict__ bias,
            void* __restrict__ C, int cMode, int epi, int bPerm, int cT,
            const int* __restrict__ dtFlag,
            int M, int N, int K, long sA, int divA, long sB, int modB, long sBias)
{
  __shared__ float As[16][65];
  __shared__ float Bs[16][65];
  const int fl = *dtFlag;
  const int aB = (aMode == 2) ? fl : aMode;
  const int cB = (cMode == 2) ? fl : cMode;
  const int t = threadIdx.x;
  const int bz = blockIdx.z;
  const long aOff = (long)(bz / divA) * sA;
  const long bOff = (long)(bz % modB) * sB;
  const long biasOff = (long)(bz % modB) * sBias;
  const long cOff = (long)bz * M * N;
  const int m0 = blockIdx.y * 64, n0 = blockIdx.x * 64;
  const int tm = t >> 4, tn = t & 15;
  const int am = t >> 2, ak = (t & 3) * 4;
  const int bkr = t >> 4, bn = (t & 15) * 4;
  float acc[4][4] = {};
  for (int k0 = 0; k0 < K; k0 += 16) {
#pragma unroll
    for (int j = 0; j < 4; j++)
      As[ak + j][am] = ldx(A, aOff + (long)(m0 + am) * K + (k0 + ak + j), aB);
    {
      int k = k0 + bkr;
      int krow = bPerm ? (((k & 255) << 3) | (k >> 8)) : k;
#pragma unroll
      for (int j = 0; j < 4; j++)
        Bs[bkr][bn + j] = ldx(B, bOff + (long)krow * N + (n0 + bn + j), fl);
    }
    __syncthreads();
#pragma unroll
    for (int kk = 0; kk < 16; kk++) {
      float a[4], b[4];
#pragma unroll
      for (int i = 0; i < 4; i++) a[i] = As[kk][tm * 4 + i];
#pragma unroll
      for (int j = 0; j < 4; j++) b[j] = Bs[kk][tn * 4 + j];
#pragma unroll
      for (int i = 0; i < 4; i++)
#pragma unroll
        for (int j = 0; j < 4; j++) acc[i][j] += a[i] * b[j];
    }
    __syncthreads();
  }
#pragma unroll
  for (int i = 0; i < 4; i++) {
    int m = m0 + tm * 4 + i;
#pragma unroll
    for (int j = 0; j < 4; j++) {
      int n = n0 + tn * 4 + j;
      float c = acc[i][j];
      if (epi >= 1) c += ldx(bias, biasOff + n, fl);
      if (epi == 2) c = fmaxf(c, 0.f);
      long idx = cT ? (cOff + (long)n * M + m) : (cOff + (long)m * N + n);
      stx(C, idx, c, cB);
    }
  }
}

__global__ __launch_bounds__(256)
void fixup_h1(float* __restrict__ h1, const void* __restrict__ label,
              const void* __restrict__ W1, const void* __restrict__ b1,
              const int* __restrict__ dtFlag)
{
  const int fl = *dtFlag;
  int idx = blockIdx.x * 256 + threadIdx.x;
  int m = idx >> 8, n = idx & 255;
  float c = h1[idx] + ldx(b1, n, fl);
#pragma unroll
  for (int j = 0; j < 3; j++)
    c += ldx(label, m * 3 + j, fl) * ldx(W1, (256 + j) * 256 + n, fl);
  h1[idx] = fmaxf(c, 0.f);
}

__global__ __launch_bounds__(64)
void diag_kernel(const bf16* __restrict__ X, float* __restrict__ diag)
{
  int r = blockIdx.x, lane = threadIdx.x;
  uint2 u = ((const uint2*)(X + (long)r * 256))[lane];
  float a = bf2f((unsigned short)(u.x & 0xffff)), b2 = bf2f((unsigned short)(u.x >> 16));
  float c = bf2f((unsigned short)(u.y & 0xffff)), d = bf2f((unsigned short)(u.y >> 16));
  float s = a * a + b2 * b2 + c * c + d * d;
#pragma unroll
  for (int off = 32; off > 0; off >>= 1) s += __shfl_down(s, off);
  if (lane == 0) diag[r] = DIAG_SC * s;
}

// ------------------------------------------------------------------
// Key-side fused, MFMA. Per (bz, f-tile 32), n-chunks of 32:
//  Phase A: DD = k@projT (4 waves x (mi,fi) quarter, 8 chained mfma),
//           E = exp(DN*dd - diag) -> pS[f][n] (transposed store, us4)
//  Phase B: ctx[f][e] += P^T @ v : A = pS[f][n], B = vS[e][n] (from vT)
//  ksum/max from phase-A fragments via shfl_xor quad-reduce.
//  Writes ctxT[bz][e][FP] (f-contiguous us4 stores).
// ------------------------------------------------------------------
__global__ __launch_bounds__(256)
void key_fused_mfma(const bf16* __restrict__ k, const bf16* __restrict__ vT,
                    const bf16* __restrict__ projB, const float* __restrict__ diagk,
                    float* __restrict__ ksumE, bf16* __restrict__ ctxT,
                    float* __restrict__ mpart)
{
  __shared__ bf16 kS[32 * 264];
  __shared__ bf16 projS[32 * 264];
  __shared__ bf16 vS[256 * 40];
  __shared__ bf16 pS[32 * 40];      // [f][n], stride 40 (80B, 16B-aligned)
  __shared__ float dS[32];
  __shared__ float redS[2][32];
  __shared__ float redM[2][32];

  const int bz = blockIdx.y, ft = blockIdx.x, f0 = ft * 32;
  const int t = threadIdx.x;
  const int w = t >> 6, l = t & 63, quad = l >> 4, ln = l & 15;
  const int mi = w & 1, fi = w >> 1;

  // stage proj tile once: [32 f][256 d]
  {
    const int row = t >> 3, ch = (t & 7) * 32;
    const uint4* src = (const uint4*)(projB + (long)(f0 + row) * 256 + ch);
    uint4* dst = (uint4*)(&projS[row * 264 + ch]);
#pragma unroll
    for (int i = 0; i < 4; i++) dst[i] = src[i];
  }
  const bf16* kb = k + (long)bz * NC * 256;
  const bf16* vtb = vT + (long)bz * 256 * NC;
  const float* db = diagk + bz * NC;

  f32x4 acc[2][4] = {};          // [fh][ei]: f=16fh+quad*4+r, e=64w+16ei+ln
  float ksumP = 0.f, mP = -1e30f;
  const bool fv = (f0 + 16 * fi + ln) < NBF;

  for (int n0 = 0; n0 < NC; n0 += 32) {
    {
      const int row = t >> 3, ch = (t & 7) * 32;
      const uint4* src = (const uint4*)(kb + (long)(n0 + row) * 256 + ch);
      uint4* dst = (uint4*)(&kS[row * 264 + ch]);
#pragma unroll
      for (int i = 0; i < 4; i++) dst[i] = src[i];
    }
    {
      // vS[e=t][n0..n0+31]: 32 bf16 = 4 x uint4  (round-5 bug: was only 2!)
      const uint4* src = (const uint4*)(vtb + (long)t * NC + n0);
      uint4* dst = (uint4*)(&vS[t * 40]);
#pragma unroll
      for (int i = 0; i < 4; i++) dst[i] = src[i];
    }
    if (t < 32) dS[t] = db[n0 + t];
    __syncthreads();

    // phase A: quarter (mi, fi): rows n=16mi+, cols f=16fi+
    f32x4 dd = {};
#pragma unroll
    for (int kc = 0; kc < 8; kc++) {
      short8 a = *(const short8*)(&kS[(16 * mi + ln) * 264 + kc * 32 + quad * 8]);
      short8 b = *(const short8*)(&projS[(16 * fi + ln) * 264 + kc * 32 + quad * 8]);
      dd = __builtin_amdgcn_mfma_f32_16x16x32_bf16(a, b, dd, 0, 0, 0);
    }
    us4 ev;
#pragma unroll
    for (int r = 0; r < 4; r++) {
      float sc = DN * dd[r];
      float E = fv ? __expf(fminf(sc - dS[16 * mi + quad * 4 + r], 80.f)) : 0.f;
      unsigned short u = f2bu(E);
      ksumP += bf2f(u);
      if (fv) mP = fmaxf(mP, sc);
      ev[r] = u;
    }
    *(us4*)(&pS[(16 * fi + ln) * 40 + 16 * mi + quad * 4]) = ev;
    __syncthreads();

    // phase B: wave w covers e in [64w, 64w+64), both f halves
#pragma unroll
    for (int fh = 0; fh < 2; fh++) {
      short8 a = *(const short8*)(&pS[(16 * fh + ln) * 40 + quad * 8]);
#pragma unroll
      for (int ei = 0; ei < 4; ei++) {
        short8 b = *(const short8*)(&vS[(64 * w + 16 * ei + ln) * 40 + quad * 8]);
        acc[fh][ei] = __builtin_amdgcn_mfma_f32_16x16x32_bf16(a, b, acc[fh][ei], 0, 0, 0);
      }
    }
    __syncthreads();
  }

  // ctxT stores: f-contiguous packs of 4
#pragma unroll
  for (int fh = 0; fh < 2; fh++) {
#pragma unroll
    for (int ei = 0; ei < 4; ei++) {
      int e = 64 * w + 16 * ei + ln;
      us4 cv;
#pragma unroll
      for (int r = 0; r < 4; r++) cv[r] = f2bu(acc[fh][ei][r]);
      *(us4*)(&ctxT[((long)bz * 256 + e) * FP + f0 + 16 * fh + quad * 4]) = cv;
    }
  }

  // ksum / max reductions
  float s = ksumP, m = mP;
  s += __shfl_xor(s, 16); s += __shfl_xor(s, 32);
  m = fmaxf(m, __shfl_xor(m, 16)); m = fmaxf(m, __shfl_xor(m, 32));
  if (quad == 0) { redS[mi][16 * fi + ln] = s; redM[mi][16 * fi + ln] = m; }
  __syncthreads();
  if (t < 32 && (f0 + t) < NBF)
    ksumE[(long)bz * NBF + f0 + t] = redS[0][t] + redS[1][t];
  if (t < 64) {
    float mm = (l < 32) ? fmaxf(redM[0][l], redM[1][l]) : -1e30f;
#pragma unroll
    for (int off = 32; off > 0; off >>= 1) mm = fmaxf(mm, __shfl_down(mm, off));
    if (l == 0) mpart[bz * 45 + ft] = mm;
  }
}

__global__ __launch_bounds__(64)
void mk_reduce(const float* __restrict__ mpart, float* __restrict__ mk)
{
  int bz = blockIdx.x, l = threadIdx.x;
  float m = (l < 45) ? mpart[bz * 45 + l] : -1e30f;
#pragma unroll
  for (int off = 32; off > 0; off >>= 1) m = fmaxf(m, __shfl_down(m, off));
  if (l == 0) mk[bz] = m;
}

// Sv from transposed vT: thread e sums its contiguous row
__global__ __launch_bounds__(256)
void sv_kernel_T(const bf16* __restrict__ vT, float* __restrict__ Sv)
{
  int bz = blockIdx.x, e = threadIdx.x;
  const uint4* r4 = (const uint4*)(vT + ((long)bz * 256 + e) * NC);
  float s = 0.f;
  for (int i = 0; i < 64; i++) {
    float tmp[8];
    unpack8(r4[i], tmp);
#pragma unroll
    for (int j = 0; j < 8; j++) s += tmp[j];
  }
  Sv[bz * 256 + e] = s;
}

// ctxT finalize: f<NBF: x = emk*x + EPS*Sv ; f>=NBF: 0
__global__ __launch_bounds__(256)
void ctx_finT(bf16* __restrict__ ctxT, const float* __restrict__ Sv,
              const float* __restrict__ mk)
{
  int e = blockIdx.x, bz = blockIdx.y, t = threadIdx.x;
  float emk = __expf(-mk[bz]);
  float sve = EPS_ * Sv[bz * 256 + e];
  bf16* row = ctxT + ((long)bz * 256 + e) * FP;
  for (int f = t; f < FP; f += 256) {
    float val = (f < NBF) ? (emk * tofloat(row[f]) + sve) : 0.f;
    row[f] = __float2bfloat16(val);
  }
}

__global__ __launch_bounds__(256)
void ksum_fin(float* __restrict__ ksumE, const float* __restrict__ mk,
              float* __restrict__ ksumtot)
{
  __shared__ float red[4];
  int bz = blockIdx.x, t = threadIdx.x;
  float emk = __expf(-mk[bz]);
  float s = 0.f;
  for (int f = t; f < NBF; f += 256) {
    float kf = emk * ksumE[(long)bz * NBF + f] + (float)NC * EPS_;
    ksumE[(long)bz * NBF + f] = kf;
    s += kf;
  }
#pragma unroll
  for (int off = 32; off > 0; off >>= 1) s += __shfl_down(s, off);
  if ((t & 63) == 0) red[t >> 6] = s;
  __syncthreads();
  if (t == 0) ksumtot[bz] = red[0] + red[1] + red[2] + red[3];
}

__global__ __launch_bounds__(256)
void ctxsumT_k(const bf16* __restrict__ ctxT, float* __restrict__ ctxsum)
{
  int bz = blockIdx.x, e = threadIdx.x;
  const bf16* row = ctxT + ((long)bz * 256 + e) * FP;
  const uint4* r4 = (const uint4*)row;
  float s = 0.f;
  for (int i = 0; i < 180; i++) {       // 180*8 = 1440, tail is zeroed
    float tmp[8];
    unpack8(r4[i], tmp);
#pragma unroll
    for (int j = 0; j < 8; j++) s += tmp[j];
  }
  ctxsum[bz * 256 + e] = s;
}

// ------------------------------------------------------------------
// Query-side fused, MFMA. Writes merged layout [t][n][h][e]
// (m = t*512+n, k = h*256+e; Wo GEMM maps k -> logical row e*8+h).
// ------------------------------------------------------------------
__global__ __launch_bounds__(256)
void q_fused_mfma(const bf16* __restrict__ q, const bf16* __restrict__ projB,
                  const float* __restrict__ diagq, const bf16* __restrict__ ctxT,
                  const float* __restrict__ ksum, const float* __restrict__ ctxsum,
                  const float* __restrict__ ksumtot, bf16* __restrict__ merged)
{
  __shared__ bf16 qS[32 * 264];
  __shared__ bf16 projS[32 * 264];
  __shared__ bf16 eS[32 * 40];
  __shared__ bf16 ctxTs[256 * 40];
  __shared__ float ksumS[32];
  __shared__ float dS[32];
  __shared__ float csS[256];
  __shared__ float sS[32][2];
  __shared__ float mS[32][2];

  const int bz = blockIdx.y, nt = blockIdx.x, t = threadIdx.x;
  const int w = t >> 6, l = t & 63, quad = l >> 4, ln = l & 15;
  const int mi = w & 1, fi = w >> 1;
  const int tq = bz / H_, hh = bz % H_;

  {
    const int row = t >> 3, ch = (t & 7) * 32;
    const uint4* src = (const uint4*)(q + ((long)bz * NT + nt * 32 + row) * 256 + ch);
    uint4* dst = (uint4*)(&qS[row * 264 + ch]);
#pragma unroll
    for (int i = 0; i < 4; i++) dst[i] = src[i];
  }
  if (t < 32) dS[t] = diagq[(long)bz * NT + nt * 32 + t];
  csS[t] = ctxsum[bz * 256 + t];

  f32x4 acc[2][4] = {};
  float sPart[4] = {0.f, 0.f, 0.f, 0.f};
  float mPart[4] = {0.f, 0.f, 0.f, 0.f};
  __syncthreads();

  for (int ft = 0; ft < 45; ft++) {
    const int f0 = ft * 32;
    {
      const int row = t >> 3, ch = (t & 7) * 32;
      const uint4* src = (const uint4*)(projB + (long)(f0 + row) * 256 + ch);
      uint4* dst = (uint4*)(&projS[row * 264 + ch]);
#pragma unroll
      for (int i = 0; i < 4; i++) dst[i] = src[i];
    }
    {
      const uint4* src = (const uint4*)(ctxT + ((long)bz * 256 + t) * FP + f0);
      uint4* dst = (uint4*)(&ctxTs[t * 40]);
#pragma unroll
      for (int i = 0; i < 4; i++) dst[i] = src[i];
    }
    if (t < 32) ksumS[t] = (f0 + t < NBF) ? ksum[(long)bz * NBF + f0 + t] : 0.f;
    __syncthreads();

    f32x4 dd = {};
#pragma unroll
    for (int kc = 0; kc < 8; kc++) {
      short8 a = *(const short8*)(&qS[(16 * mi + ln) * 264 + kc * 32 + quad * 8]);
      short8 b = *(const short8*)(&projS[(16 * fi + ln) * 264 + kc * 32 + quad * 8]);
      dd = __builtin_amdgcn_mfma_f32_16x16x32_bf16(a, b, dd, 0, 0, 0);
    }
    const bool fv = (f0 + 16 * fi + ln) < NBF;
    const float kv = ksumS[16 * fi + ln];
#pragma unroll
    for (int r = 0; r < 4; r++) {
      float E = fv ? __expf(fminf(DN * dd[r], 80.f)) : 0.f;
      bf16 h = __float2bfloat16(E);
      float Er = tofloat(h);
      eS[(16 * mi + quad * 4 + r) * 40 + 16 * fi + ln] = h;
      sPart[r] += Er * kv;
      mPart[r] = fmaxf(mPart[r], Er);
    }
    __syncthreads();

#pragma unroll
    for (int mh = 0; mh < 2; mh++) {
      short8 a = *(const short8*)(&eS[(16 * mh + ln) * 40 + quad * 8]);
#pragma unroll
      for (int i = 0; i < 4; i++) {
        short8 b = *(const short8*)(&ctxTs[(16 * (4 * w + i) + ln) * 40 + quad * 8]);
        acc[mh][i] = __builtin_amdgcn_mfma_f32_16x16x32_bf16(a, b, acc[mh][i], 0, 0, 0);
      }
    }
    __syncthreads();
  }

#pragma unroll
  for (int r = 0; r < 4; r++) {
    float s = sPart[r], m = mPart[r];
#pragma unroll
    for (int off = 1; off < 16; off <<= 1) {
      s += __shfl_xor(s, off);
      m = fmaxf(m, __shfl_xor(m, off));
    }
    if (ln == 0) {
      sS[16 * mi + quad * 4 + r][fi] = s;
      mS[16 * mi + quad * 4 + r][fi] = m;
    }
  }
  __syncthreads();

  const float ktotv = ksumtot[bz];
#pragma unroll
  for (int mh = 0; mh < 2; mh++) {
#pragma unroll
    for (int r = 0; r < 4; r++) {
      int row = 16 * mh + quad * 4 + r;
      float st = sS[row][0] + sS[row][1];
      float mt = fmaxf(fmaxf(mS[row][0], mS[row][1]), 1e-30f);
      float c = __expf(-dS[row]) / mt;
      float inv = 1.f / (c * st + EPS_ * ktotv);
#pragma unroll
      for (int i = 0; i < 4; i++) {
        int e = 16 * (4 * w + i) + ln;
        float val = (c * acc[mh][i][r] + EPS_ * csS[e]) * inv;
        // merged layout [t][n][h][e]: m = t*512+n, k = h*256+e
        merged[((long)tq * NT + nt * 32 + row) * 2048 + hh * 256 + e] =
            __float2bfloat16(val);
      }
    }
  }
}

// ------------------------------------------------------------------
extern "C" void kernel_launch(void* const* d_in, const int* in_sizes, int n_in,
                              void* d_out, int out_size, void* d_ws, size_t ws_size,
                              hipStream_t stream)
{
  const void* x_ctx = d_in[0];
  const void* label = d_in[1];
  const void* x_tgt = d_in[2];
  const void* W1 = d_in[3];
  const void* b1 = d_in[4];
  const void* W2 = d_in[5];
  const void* b2 = d_in[6];
  const void* W3 = d_in[7];
  const void* b3 = d_in[8];
  const void* Wk = d_in[9];
  const void* bk = d_in[10];
  const void* Wv = d_in[11];
  const void* bv = d_in[12];
  const void* Wq = d_in[13];
  const void* bq = d_in[14];
  const void* Wo = d_in[15];
  const void* bo = d_in[16];
  const void* Wmu = d_in[17];
  const void* bmu = d_in[18];
  const void* proj = d_in[19];

  // Arena (floats), peak ~82 MB:
  //  F0: kB bf16 -> qB bf16 -> rep fp32
  //  F1: vT bf16 [64][256][512] -> merged bf16 [t][n][h][e]
  //  F2: h1,h2,cf fp32 -> ctxT bf16 [64][256][FP]
  //  F3: tail
  float* W = (float*)d_ws;
  const long F0 = 0, F1 = 4194304, F2 = 8388608;
  const long CTXT_F = (long)64 * 256 * FP / 2;   // 11,796,480 floats
  const long F3 = F2 + CTXT_F;
  bf16* kB = (bf16*)(W + F0);
  bf16* qB = (bf16*)(W + F0);
  float* rep = W + F0;
  bf16* vT = (bf16*)(W + F1);
  bf16* merged = (bf16*)(W + F1);
  float* h1 = W + F2;
  float* h2 = W + F2 + 1048576;
  float* cf = W + F2 + 2097152;
  bf16* ctxT = (bf16*)(W + F2);
  long o = F3;
  auto alloc = [&](long n) { float* p = W + o; o += n; return p; };
  float* dgk = alloc(32768);
  float* dgq = alloc(32768);
  float* ksumE = alloc((long)64 * NBF);
  float* mpart = alloc(64 * 45);
  float* mk = alloc(64);
  float* Sv = alloc(64 * 256);
  float* ctxs = alloc(64 * 256);
  float* ktot = alloc(64);
  int* dtFlag = (int*)alloc(64);
  bf16* projB = (bf16*)alloc((long)FP * 256 / 2);
  (void)ws_size; (void)in_sizes; (void)n_in; (void)out_size;

  const dim3 B(256);
  detect_dtype<<<1, B, 0, stream>>>(x_ctx, dtFlag);
  conv_proj<<<FP, B, 0, stream>>>(proj, projB, dtFlag);
  // 1. task-encoder MLP
  gemm_k<<<dim3(4, 64, 1), B, 0, stream>>>(
      x_ctx, 2, W1, nullptr, h1, 0, 0, 0, 0, dtFlag, 4096, 256, 256, 0L, 1, 0L, 1, 0L);
  fixup_h1<<<4096, B, 0, stream>>>(h1, label, W1, b1, dtFlag);
  gemm_k<<<dim3(4, 64, 1), B, 0, stream>>>(
      h1, 0, W2, b2, h2, 0, 2, 0, 0, dtFlag, 4096, 256, 256, 0L, 1, 0L, 1, 0L);
  gemm_k<<<dim3(4, 64, 1), B, 0, stream>>>(
      h2, 0, W3, b3, cf, 0, 2, 0, 0, dtFlag, 4096, 256, 256, 0L, 1, 0L, 1, 0L);
  // 2. k projection (natural), v projection (transposed out -> vT)
  gemm_k<<<dim3(4, 8, 64), B, 0, stream>>>(
      x_ctx, 2, Wk, bk, kB, 1, 1, 0, 0, dtFlag, 512, 256, 256, (long)512 * 256, H_, 65536L, H_, 256L);
  gemm_k<<<dim3(4, 8, 64), B, 0, stream>>>(
      cf, 0, Wv, bv, vT, 1, 1, 0, 1, dtFlag, 512, 256, 256, (long)512 * 256, H_, 65536L, H_, 256L);
  // 3. key side (MFMA)
  diag_kernel<<<32768, 64, 0, stream>>>(kB, dgk);
  key_fused_mfma<<<dim3(45, 64), B, 0, stream>>>(kB, vT, projB, dgk, ksumE, ctxT, mpart);
  mk_reduce<<<64, 64, 0, stream>>>(mpart, mk);
  sv_kernel_T<<<64, B, 0, stream>>>(vT, Sv);
  ctx_finT<<<dim3(256, 64), B, 0, stream>>>(ctxT, Sv, mk);
  ksum_fin<<<64, B, 0, stream>>>(ksumE, mk, ktot);
  ctxsumT_k<<<64, B, 0, stream>>>(ctxT, ctxs);
  // 4. q projection + diag
  gemm_k<<<dim3(4, 8, 64), B, 0, stream>>>(
      x_tgt, 2, Wq, bq, qB, 1, 1, 0, 0, dtFlag, 512, 256, 256, (long)512 * 256, H_, 65536L, H_, 256L);
  diag_kernel<<<32768, 64, 0, stream>>>(qB, dgq);
  // 5. query side (MFMA) -> merged [t][n][h][e]
  q_fused_mfma<<<dim3(16, 64), B, 0, stream>>>(qB, projB, dgq, ctxT, ksumE, ctxs, ktot, merged);
  // 6. output projections (Wo rows permuted: k=h*256+e -> logical e*8+h)
  gemm_k<<<dim3(4, 64, 1), B, 0, stream>>>(
      merged, 1, Wo, bo, rep, 0, 1, 1, 0, dtFlag, 4096, 256, 2048, 0L, 1, 0L, 1, 0L);
  gemm_k<<<dim3(4, 64, 1), B, 0, stream>>>(
      rep, 0, Wmu, bmu, d_out, 2, 1, 0, 0, dtFlag, 4096, 256, 256, 0L, 1, 0L, 1, 0L);
}

// Round 7
// 853.523 us; speedup vs baseline: 5.4426x; 1.6562x over previous
//
#include <hip/hip_runtime.h>
#include <hip/hip_bf16.h>

typedef __hip_bfloat16 bf16;
typedef __attribute__((ext_vector_type(8))) short short8;
typedef __attribute__((ext_vector_type(4))) float f32x4;
typedef __attribute__((ext_vector_type(4))) unsigned short us4;
#define DEV __device__ __forceinline__

static constexpr int T_ = 8, NC = 512, NT = 512, D_ = 256, H_ = 8, NBF = 1419;
static constexpr int FP = 1440;             // padded F (45*32), zero-filled tail
static constexpr float EPS_ = 1e-4f;
static constexpr float DN = 0.25f;          // D^-0.25
static constexpr float DIAG_SC = 0.03125f;  // 0.5 * DN^2

DEV float bf2f(unsigned short u) { return __uint_as_float(((unsigned)u) << 16); }
DEV float tofloat(bf16 x) { return __bfloat162float(x); }
DEV unsigned short f2bu(float x) { bf16 h = __float2bfloat16(x); return *(unsigned short*)&h; }

DEV float ldx(const void* p, long i, int isb) {
  if (isb) return bf2f(((const unsigned short*)p)[i]);
  return ((const float*)p)[i];
}
DEV void stx(void* p, long i, float v, int isb) {
  if (isb) ((bf16*)p)[i] = __float2bfloat16(v);
  else     ((float*)p)[i] = v;
}
DEV void unpack8(uint4 u, float* dst) {
  unsigned w[4] = {u.x, u.y, u.z, u.w};
#pragma unroll
  for (int i = 0; i < 4; i++) {
    dst[2 * i + 0] = __uint_as_float((w[i] & 0xffffu) << 16);
    dst[2 * i + 1] = __uint_as_float(w[i] & 0xffff0000u);
  }
}

// ------------------------------------------------------------------
// dtype probe (1 = bf16 inputs, 0 = fp32)
// ------------------------------------------------------------------
__global__ __launch_bounds__(256)
void detect_dtype(const void* __restrict__ x, int* __restrict__ flag)
{
  __shared__ int bad;
  if (threadIdx.x == 0) bad = 0;
  __syncthreads();
  int mybad = 0;
  for (int j = 0; j < 16; j++) {
    long i = 2L * (threadIdx.x + 256L * j);
    unsigned short u = ((const unsigned short*)x)[i];
    int e = (u >> 7) & 0xff, mant = u & 0x7f;
    bool b = (e == 0xff) || (e >= 141) || (e <= 93 && !(e == 0 && mant == 0));
    mybad += b ? 1 : 0;
  }
  atomicAdd(&bad, mybad);
  __syncthreads();
  if (threadIdx.x == 0) *flag = (bad > 1024) ? 0 : 1;
}

// proj -> bf16 [FP][256], zero rows past NBF
__global__ __launch_bounds__(256)
void conv_proj(const void* __restrict__ proj, bf16* __restrict__ projB,
               const int* __restrict__ dtFlag)
{
  const int fl = *dtFlag;
  int f = blockIdx.x, t = threadIdx.x;
  float v = (f < NBF) ? ldx(proj, (long)f * 256 + t, fl) : 0.f;
  projB[(long)f * 256 + t] = __float2bfloat16(v);
}

// ------------------------------------------------------------------
// MFMA GEMM: C[M,N] = A[M,K] @ B[K,N] (+bias)(+relu).
// Tile 64x64, K-step 32, 4 waves; wave w owns m-rows 16w..16w+15.
// aMode: 0=f32, 1=bf16, 2=dynamic; cMode same. B/bias dynamic (weights).
// bPerm: B row k -> ((k&255)<<3)|(k>>8)  (Wo head-merge fold).
// cT=1: store C transposed at cOff + n*M + m.
// M%64==0, N%64==0, K%32==0 (all calls satisfy).
// ------------------------------------------------------------------
__global__ __launch_bounds__(256)
void gemm_mfma(const void* __restrict__ A, int aMode,
               const void* __restrict__ B, const void* __restrict__ bias,
               void* __restrict__ C, int cMode, int epi, int bPerm, int cT,
               const int* __restrict__ dtFlag,
               int M, int N, int K, long sA, int divA, long sB, int modB, long sBias)
{
  __shared__ bf16 As[64 * 40];
  __shared__ bf16 Ws[64 * 40];
  const int fl = *dtFlag;
  const int aB = (aMode == 2) ? fl : aMode;
  const int cB = (cMode == 2) ? fl : cMode;
  const int t = threadIdx.x;
  const int bz = blockIdx.z;
  const long aOff = (long)(bz / divA) * sA;
  const long bOff = (long)(bz % modB) * sB;
  const long biasOff = (long)(bz % modB) * sBias;
  const long cOff = (long)bz * (long)M * N;
  const int m0 = blockIdx.y * 64, n0 = blockIdx.x * 64;
  const int w = t >> 6, l = t & 63, quad = l >> 4, ln = l & 15;
  const int am = t >> 2, ak8 = (t & 3) * 8;   // A staging: row am, k-chunk ak8
  const int wk = t & 31, wg = t >> 5;         // W staging: k=wk, n-group wg*8
  f32x4 acc[4] = {};

  for (int k0 = 0; k0 < K; k0 += 32) {
    // stage A [64 m][32 k]
    if (aB == 1) {
      const uint4* src = (const uint4*)((const bf16*)A + aOff + (long)(m0 + am) * K + k0 + ak8);
      *(uint4*)(&As[am * 40 + ak8]) = *src;
    } else {
      const float* src = (const float*)A + aOff + (long)(m0 + am) * K + k0 + ak8;
      unsigned short tmp[8];
#pragma unroll
      for (int i = 0; i < 8; i++) tmp[i] = f2bu(src[i]);
      *(uint4*)(&As[am * 40 + ak8]) = *(const uint4*)tmp;
    }
    // stage W transposed [64 n][32 k]
    {
      int k = k0 + wk;
      int krow = bPerm ? (((k & 255) << 3) | (k >> 8)) : k;
      if (fl == 1) {
        uint4 u = *(const uint4*)((const bf16*)B + bOff + (long)krow * N + n0 + wg * 8);
        const unsigned short* us = (const unsigned short*)&u;
#pragma unroll
        for (int j = 0; j < 8; j++) Ws[(wg * 8 + j) * 40 + wk] = *(const bf16*)&us[j];
      } else {
        const float* src = (const float*)B + bOff + (long)krow * N + n0 + wg * 8;
#pragma unroll
        for (int j = 0; j < 8; j++) {
          unsigned short u = f2bu(src[j]);
          Ws[(wg * 8 + j) * 40 + wk] = *(const bf16*)&u;
        }
      }
    }
    __syncthreads();
    short8 a = *(const short8*)(&As[(16 * w + ln) * 40 + quad * 8]);
#pragma unroll
    for (int i = 0; i < 4; i++) {
      short8 b = *(const short8*)(&Ws[(16 * i + ln) * 40 + quad * 8]);
      acc[i] = __builtin_amdgcn_mfma_f32_16x16x32_bf16(a, b, acc[i], 0, 0, 0);
    }
    __syncthreads();
  }

#pragma unroll
  for (int i = 0; i < 4; i++) {
#pragma unroll
    for (int r = 0; r < 4; r++) {
      int m = m0 + 16 * w + quad * 4 + r;
      int n = n0 + 16 * i + ln;
      float c = acc[i][r];
      if (epi >= 1) c += ldx(bias, biasOff + n, fl);
      if (epi == 2) c = fmaxf(c, 0.f);
      long idx = cT ? (cOff + (long)n * M + m) : (cOff + (long)m * N + n);
      stx(C, idx, c, cB);
    }
  }
}

// h1 = relu(h1 + label @ W1[256:259] + b1)   (h1 bf16)
__global__ __launch_bounds__(256)
void fixup_h1(bf16* __restrict__ h1, const void* __restrict__ label,
              const void* __restrict__ W1, const void* __restrict__ b1,
              const int* __restrict__ dtFlag)
{
  const int fl = *dtFlag;
  int idx = blockIdx.x * 256 + threadIdx.x;
  int m = idx >> 8, n = idx & 255;
  float c = tofloat(h1[idx]) + ldx(b1, n, fl);
#pragma unroll
  for (int j = 0; j < 3; j++)
    c += ldx(label, m * 3 + j, fl) * ldx(W1, (256 + j) * 256 + n, fl);
  h1[idx] = __float2bfloat16(fmaxf(c, 0.f));
}

__global__ __launch_bounds__(64)
void diag_kernel(const bf16* __restrict__ X, float* __restrict__ diag)
{
  int r = blockIdx.x, lane = threadIdx.x;
  uint2 u = ((const uint2*)(X + (long)r * 256))[lane];
  float a = bf2f((unsigned short)(u.x & 0xffff)), b2 = bf2f((unsigned short)(u.x >> 16));
  float c = bf2f((unsigned short)(u.y & 0xffff)), d = bf2f((unsigned short)(u.y >> 16));
  float s = a * a + b2 * b2 + c * c + d * d;
#pragma unroll
  for (int off = 32; off > 0; off >>= 1) s += __shfl_down(s, off);
  if (lane == 0) diag[r] = DIAG_SC * s;
}

// ------------------------------------------------------------------
// Key-side fused, MFMA (unchanged from round 6).
// ------------------------------------------------------------------
__global__ __launch_bounds__(256)
void key_fused_mfma(const bf16* __restrict__ k, const bf16* __restrict__ vT,
                    const bf16* __restrict__ projB, const float* __restrict__ diagk,
                    float* __restrict__ ksumE, bf16* __restrict__ ctxT,
                    float* __restrict__ mpart)
{
  __shared__ bf16 kS[32 * 264];
  __shared__ bf16 projS[32 * 264];
  __shared__ bf16 vS[256 * 40];
  __shared__ bf16 pS[32 * 40];
  __shared__ float dS[32];
  __shared__ float redS[2][32];
  __shared__ float redM[2][32];

  const int bz = blockIdx.y, ft = blockIdx.x, f0 = ft * 32;
  const int t = threadIdx.x;
  const int w = t >> 6, l = t & 63, quad = l >> 4, ln = l & 15;
  const int mi = w & 1, fi = w >> 1;

  {
    const int row = t >> 3, ch = (t & 7) * 32;
    const uint4* src = (const uint4*)(projB + (long)(f0 + row) * 256 + ch);
    uint4* dst = (uint4*)(&projS[row * 264 + ch]);
#pragma unroll
    for (int i = 0; i < 4; i++) dst[i] = src[i];
  }
  const bf16* kb = k + (long)bz * NC * 256;
  const bf16* vtb = vT + (long)bz * 256 * NC;
  const float* db = diagk + bz * NC;

  f32x4 acc[2][4] = {};
  float ksumP = 0.f, mP = -1e30f;
  const bool fv = (f0 + 16 * fi + ln) < NBF;

  for (int n0 = 0; n0 < NC; n0 += 32) {
    {
      const int row = t >> 3, ch = (t & 7) * 32;
      const uint4* src = (const uint4*)(kb + (long)(n0 + row) * 256 + ch);
      uint4* dst = (uint4*)(&kS[row * 264 + ch]);
#pragma unroll
      for (int i = 0; i < 4; i++) dst[i] = src[i];
    }
    {
      const uint4* src = (const uint4*)(vtb + (long)t * NC + n0);
      uint4* dst = (uint4*)(&vS[t * 40]);
#pragma unroll
      for (int i = 0; i < 4; i++) dst[i] = src[i];
    }
    if (t < 32) dS[t] = db[n0 + t];
    __syncthreads();

    f32x4 dd = {};
#pragma unroll
    for (int kc = 0; kc < 8; kc++) {
      short8 a = *(const short8*)(&kS[(16 * mi + ln) * 264 + kc * 32 + quad * 8]);
      short8 b = *(const short8*)(&projS[(16 * fi + ln) * 264 + kc * 32 + quad * 8]);
      dd = __builtin_amdgcn_mfma_f32_16x16x32_bf16(a, b, dd, 0, 0, 0);
    }
    us4 ev;
#pragma unroll
    for (int r = 0; r < 4; r++) {
      float sc = DN * dd[r];
      float E = fv ? __expf(fminf(sc - dS[16 * mi + quad * 4 + r], 80.f)) : 0.f;
      unsigned short u = f2bu(E);
      ksumP += bf2f(u);
      if (fv) mP = fmaxf(mP, sc);
      ev[r] = u;
    }
    *(us4*)(&pS[(16 * fi + ln) * 40 + 16 * mi + quad * 4]) = ev;
    __syncthreads();

#pragma unroll
    for (int fh = 0; fh < 2; fh++) {
      short8 a = *(const short8*)(&pS[(16 * fh + ln) * 40 + quad * 8]);
#pragma unroll
      for (int ei = 0; ei < 4; ei++) {
        short8 b = *(const short8*)(&vS[(64 * w + 16 * ei + ln) * 40 + quad * 8]);
        acc[fh][ei] = __builtin_amdgcn_mfma_f32_16x16x32_bf16(a, b, acc[fh][ei], 0, 0, 0);
      }
    }
    __syncthreads();
  }

#pragma unroll
  for (int fh = 0; fh < 2; fh++) {
#pragma unroll
    for (int ei = 0; ei < 4; ei++) {
      int e = 64 * w + 16 * ei + ln;
      us4 cv;
#pragma unroll
      for (int r = 0; r < 4; r++) cv[r] = f2bu(acc[fh][ei][r]);
      *(us4*)(&ctxT[((long)bz * 256 + e) * FP + f0 + 16 * fh + quad * 4]) = cv;
    }
  }

  float s = ksumP, m = mP;
  s += __shfl_xor(s, 16); s += __shfl_xor(s, 32);
  m = fmaxf(m, __shfl_xor(m, 16)); m = fmaxf(m, __shfl_xor(m, 32));
  if (quad == 0) { redS[mi][16 * fi + ln] = s; redM[mi][16 * fi + ln] = m; }
  __syncthreads();
  if (t < 32 && (f0 + t) < NBF)
    ksumE[(long)bz * NBF + f0 + t] = redS[0][t] + redS[1][t];
  if (t < 64) {
    float mm = (l < 32) ? fmaxf(redM[0][l], redM[1][l]) : -1e30f;
#pragma unroll
    for (int off = 32; off > 0; off >>= 1) mm = fmaxf(mm, __shfl_down(mm, off));
    if (l == 0) mpart[bz * 45 + ft] = mm;
  }
}

__global__ __launch_bounds__(64)
void mk_reduce(const float* __restrict__ mpart, float* __restrict__ mk)
{
  int bz = blockIdx.x, l = threadIdx.x;
  float m = (l < 45) ? mpart[bz * 45 + l] : -1e30f;
#pragma unroll
  for (int off = 32; off > 0; off >>= 1) m = fmaxf(m, __shfl_down(m, off));
  if (l == 0) mk[bz] = m;
}

__global__ __launch_bounds__(256)
void sv_kernel_T(const bf16* __restrict__ vT, float* __restrict__ Sv)
{
  int bz = blockIdx.x, e = threadIdx.x;
  const uint4* r4 = (const uint4*)(vT + ((long)bz * 256 + e) * NC);
  float s = 0.f;
  for (int i = 0; i < 64; i++) {
    float tmp[8];
    unpack8(r4[i], tmp);
#pragma unroll
    for (int j = 0; j < 8; j++) s += tmp[j];
  }
  Sv[bz * 256 + e] = s;
}

__global__ __launch_bounds__(256)
void ctx_finT(bf16* __restrict__ ctxT, const float* __restrict__ Sv,
              const float* __restrict__ mk)
{
  int e = blockIdx.x, bz = blockIdx.y, t = threadIdx.x;
  float emk = __expf(-mk[bz]);
  float sve = EPS_ * Sv[bz * 256 + e];
  bf16* row = ctxT + ((long)bz * 256 + e) * FP;
  for (int f = t; f < FP; f += 256) {
    float val = (f < NBF) ? (emk * tofloat(row[f]) + sve) : 0.f;
    row[f] = __float2bfloat16(val);
  }
}

__global__ __launch_bounds__(256)
void ksum_fin(float* __restrict__ ksumE, const float* __restrict__ mk,
              float* __restrict__ ksumtot)
{
  __shared__ float red[4];
  int bz = blockIdx.x, t = threadIdx.x;
  float emk = __expf(-mk[bz]);
  float s = 0.f;
  for (int f = t; f < NBF; f += 256) {
    float kf = emk * ksumE[(long)bz * NBF + f] + (float)NC * EPS_;
    ksumE[(long)bz * NBF + f] = kf;
    s += kf;
  }
#pragma unroll
  for (int off = 32; off > 0; off >>= 1) s += __shfl_down(s, off);
  if ((t & 63) == 0) red[t >> 6] = s;
  __syncthreads();
  if (t == 0) ksumtot[bz] = red[0] + red[1] + red[2] + red[3];
}

__global__ __launch_bounds__(256)
void ctxsumT_k(const bf16* __restrict__ ctxT, float* __restrict__ ctxsum)
{
  int bz = blockIdx.x, e = threadIdx.x;
  const bf16* row = ctxT + ((long)bz * 256 + e) * FP;
  const uint4* r4 = (const uint4*)row;
  float s = 0.f;
  for (int i = 0; i < 180; i++) {
    float tmp[8];
    unpack8(r4[i], tmp);
#pragma unroll
    for (int j = 0; j < 8; j++) s += tmp[j];
  }
  ctxsum[bz * 256 + e] = s;
}

// ------------------------------------------------------------------
// Query-side fused, MFMA (unchanged from round 6). merged [t][n][h][e].
// ------------------------------------------------------------------
__global__ __launch_bounds__(256)
void q_fused_mfma(const bf16* __restrict__ q, const bf16* __restrict__ projB,
                  const float* __restrict__ diagq, const bf16* __restrict__ ctxT,
                  const float* __restrict__ ksum, const float* __restrict__ ctxsum,
                  const float* __restrict__ ksumtot, bf16* __restrict__ merged)
{
  __shared__ bf16 qS[32 * 264];
  __shared__ bf16 projS[32 * 264];
  __shared__ bf16 eS[32 * 40];
  __shared__ bf16 ctxTs[256 * 40];
  __shared__ float ksumS[32];
  __shared__ float dS[32];
  __shared__ float csS[256];
  __shared__ float sS[32][2];
  __shared__ float mS[32][2];

  const int bz = blockIdx.y, nt = blockIdx.x, t = threadIdx.x;
  const int w = t >> 6, l = t & 63, quad = l >> 4, ln = l & 15;
  const int mi = w & 1, fi = w >> 1;
  const int tq = bz / H_, hh = bz % H_;

  {
    const int row = t >> 3, ch = (t & 7) * 32;
    const uint4* src = (const uint4*)(q + ((long)bz * NT + nt * 32 + row) * 256 + ch);
    uint4* dst = (uint4*)(&qS[row * 264 + ch]);
#pragma unroll
    for (int i = 0; i < 4; i++) dst[i] = src[i];
  }
  if (t < 32) dS[t] = diagq[(long)bz * NT + nt * 32 + t];
  csS[t] = ctxsum[bz * 256 + t];

  f32x4 acc[2][4] = {};
  float sPart[4] = {0.f, 0.f, 0.f, 0.f};
  float mPart[4] = {0.f, 0.f, 0.f, 0.f};
  __syncthreads();

  for (int ft = 0; ft < 45; ft++) {
    const int f0 = ft * 32;
    {
      const int row = t >> 3, ch = (t & 7) * 32;
      const uint4* src = (const uint4*)(projB + (long)(f0 + row) * 256 + ch);
      uint4* dst = (uint4*)(&projS[row * 264 + ch]);
#pragma unroll
      for (int i = 0; i < 4; i++) dst[i] = src[i];
    }
    {
      const uint4* src = (const uint4*)(ctxT + ((long)bz * 256 + t) * FP + f0);
      uint4* dst = (uint4*)(&ctxTs[t * 40]);
#pragma unroll
      for (int i = 0; i < 4; i++) dst[i] = src[i];
    }
    if (t < 32) ksumS[t] = (f0 + t < NBF) ? ksum[(long)bz * NBF + f0 + t] : 0.f;
    __syncthreads();

    f32x4 dd = {};
#pragma unroll
    for (int kc = 0; kc < 8; kc++) {
      short8 a = *(const short8*)(&qS[(16 * mi + ln) * 264 + kc * 32 + quad * 8]);
      short8 b = *(const short8*)(&projS[(16 * fi + ln) * 264 + kc * 32 + quad * 8]);
      dd = __builtin_amdgcn_mfma_f32_16x16x32_bf16(a, b, dd, 0, 0, 0);
    }
    const bool fv = (f0 + 16 * fi + ln) < NBF;
    const float kv = ksumS[16 * fi + ln];
#pragma unroll
    for (int r = 0; r < 4; r++) {
      float E = fv ? __expf(fminf(DN * dd[r], 80.f)) : 0.f;
      bf16 h = __float2bfloat16(E);
      float Er = tofloat(h);
      eS[(16 * mi + quad * 4 + r) * 40 + 16 * fi + ln] = h;
      sPart[r] += Er * kv;
      mPart[r] = fmaxf(mPart[r], Er);
    }
    __syncthreads();

#pragma unroll
    for (int mh = 0; mh < 2; mh++) {
      short8 a = *(const short8*)(&eS[(16 * mh + ln) * 40 + quad * 8]);
#pragma unroll
      for (int i = 0; i < 4; i++) {
        short8 b = *(const short8*)(&ctxTs[(16 * (4 * w + i) + ln) * 40 + quad * 8]);
        acc[mh][i] = __builtin_amdgcn_mfma_f32_16x16x32_bf16(a, b, acc[mh][i], 0, 0, 0);
      }
    }
    __syncthreads();
  }

#pragma unroll
  for (int r = 0; r < 4; r++) {
    float s = sPart[r], m = mPart[r];
#pragma unroll
    for (int off = 1; off < 16; off <<= 1) {
      s += __shfl_xor(s, off);
      m = fmaxf(m, __shfl_xor(m, off));
    }
    if (ln == 0) {
      sS[16 * mi + quad * 4 + r][fi] = s;
      mS[16 * mi + quad * 4 + r][fi] = m;
    }
  }
  __syncthreads();

  const float ktotv = ksumtot[bz];
#pragma unroll
  for (int mh = 0; mh < 2; mh++) {
#pragma unroll
    for (int r = 0; r < 4; r++) {
      int row = 16 * mh + quad * 4 + r;
      float st = sS[row][0] + sS[row][1];
      float mt = fmaxf(fmaxf(mS[row][0], mS[row][1]), 1e-30f);
      float c = __expf(-dS[row]) / mt;
      float inv = 1.f / (c * st + EPS_ * ktotv);
#pragma unroll
      for (int i = 0; i < 4; i++) {
        int e = 16 * (4 * w + i) + ln;
        float val = (c * acc[mh][i][r] + EPS_ * csS[e]) * inv;
        merged[((long)tq * NT + nt * 32 + row) * 2048 + hh * 256 + e] =
            __float2bfloat16(val);
      }
    }
  }
}

// ------------------------------------------------------------------
extern "C" void kernel_launch(void* const* d_in, const int* in_sizes, int n_in,
                              void* d_out, int out_size, void* d_ws, size_t ws_size,
                              hipStream_t stream)
{
  const void* x_ctx = d_in[0];
  const void* label = d_in[1];
  const void* x_tgt = d_in[2];
  const void* W1 = d_in[3];
  const void* b1 = d_in[4];
  const void* W2 = d_in[5];
  const void* b2 = d_in[6];
  const void* W3 = d_in[7];
  const void* b3 = d_in[8];
  const void* Wk = d_in[9];
  const void* bk = d_in[10];
  const void* Wv = d_in[11];
  const void* bv = d_in[12];
  const void* Wq = d_in[13];
  const void* bq = d_in[14];
  const void* Wo = d_in[15];
  const void* bo = d_in[16];
  const void* Wmu = d_in[17];
  const void* bmu = d_in[18];
  const void* proj = d_in[19];

  // Arena (floats), peak ~82 MB:
  //  F0: kB bf16 -> qB bf16 -> rep bf16
  //  F1: vT bf16 [64][256][512] -> merged bf16 [t][n][h][e]
  //  F2: h1,h2,cf bf16 -> ctxT bf16 [64][256][FP]
  //  F3: tail
  float* W = (float*)d_ws;
  const long F0 = 0, F1 = 4194304, F2 = 8388608;
  const long CTXT_F = (long)64 * 256 * FP / 2;   // 11,796,480 floats
  const long F3 = F2 + CTXT_F;
  bf16* kB = (bf16*)(W + F0);
  bf16* qB = (bf16*)(W + F0);
  bf16* rep = (bf16*)(W + F0);
  bf16* vT = (bf16*)(W + F1);
  bf16* merged = (bf16*)(W + F1);
  bf16* h1 = (bf16*)(W + F2);
  bf16* h2 = (bf16*)(W + F2 + 524288);
  bf16* cf = (bf16*)(W + F2 + 1048576);
  bf16* ctxT = (bf16*)(W + F2);
  long o = F3;
  auto alloc = [&](long n) { float* p = W + o; o += n; return p; };
  float* dgk = alloc(32768);
  float* dgq = alloc(32768);
  float* ksumE = alloc((long)64 * NBF);
  float* mpart = alloc(64 * 45);
  float* mk = alloc(64);
  float* Sv = alloc(64 * 256);
  float* ctxs = alloc(64 * 256);
  float* ktot = alloc(64);
  int* dtFlag = (int*)alloc(64);
  bf16* projB = (bf16*)alloc((long)FP * 256 / 2);
  (void)ws_size; (void)in_sizes; (void)n_in; (void)out_size;

  const dim3 B(256);
  detect_dtype<<<1, B, 0, stream>>>(x_ctx, dtFlag);
  conv_proj<<<FP, B, 0, stream>>>(proj, projB, dtFlag);
  // 1. task-encoder MLP (bf16 activations)
  gemm_mfma<<<dim3(4, 64, 1), B, 0, stream>>>(
      x_ctx, 2, W1, nullptr, h1, 1, 0, 0, 0, dtFlag, 4096, 256, 256, 0L, 1, 0L, 1, 0L);
  fixup_h1<<<4096, B, 0, stream>>>(h1, label, W1, b1, dtFlag);
  gemm_mfma<<<dim3(4, 64, 1), B, 0, stream>>>(
      h1, 1, W2, b2, h2, 1, 2, 0, 0, dtFlag, 4096, 256, 256, 0L, 1, 0L, 1, 0L);
  gemm_mfma<<<dim3(4, 64, 1), B, 0, stream>>>(
      h2, 1, W3, b3, cf, 1, 2, 0, 0, dtFlag, 4096, 256, 256, 0L, 1, 0L, 1, 0L);
  // 2. k projection (natural), v projection (transposed -> vT)
  gemm_mfma<<<dim3(4, 8, 64), B, 0, stream>>>(
      x_ctx, 2, Wk, bk, kB, 1, 1, 0, 0, dtFlag, 512, 256, 256, (long)512 * 256, H_, 65536L, H_, 256L);
  gemm_mfma<<<dim3(4, 8, 64), B, 0, stream>>>(
      cf, 1, Wv, bv, vT, 1, 1, 0, 1, dtFlag, 512, 256, 256, (long)512 * 256, H_, 65536L, H_, 256L);
  // 3. key side (MFMA)
  diag_kernel<<<32768, 64, 0, stream>>>(kB, dgk);
  key_fused_mfma<<<dim3(45, 64), B, 0, stream>>>(kB, vT, projB, dgk, ksumE, ctxT, mpart);
  mk_reduce<<<64, 64, 0, stream>>>(mpart, mk);
  sv_kernel_T<<<64, B, 0, stream>>>(vT, Sv);
  ctx_finT<<<dim3(256, 64), B, 0, stream>>>(ctxT, Sv, mk);
  ksum_fin<<<64, B, 0, stream>>>(ksumE, mk, ktot);
  ctxsumT_k<<<64, B, 0, stream>>>(ctxT, ctxs);
  // 4. q projection + diag
  gemm_mfma<<<dim3(4, 8, 64), B, 0, stream>>>(
      x_tgt, 2, Wq, bq, qB, 1, 1, 0, 0, dtFlag, 512, 256, 256, (long)512 * 256, H_, 65536L, H_, 256L);
  diag_kernel<<<32768, 64, 0, stream>>>(qB, dgq);
  // 5. query side (MFMA) -> merged [t][n][h][e]
  q_fused_mfma<<<dim3(16, 64), B, 0, stream>>>(qB, projB, dgq, ctxT, ksumE, ctxs, ktot, merged);
  // 6. output projections (Wo rows permuted: k=h*256+e -> logical e*8+h)
  gemm_mfma<<<dim3(4, 64, 1), B, 0, stream>>>(
      merged, 1, Wo, bo, rep, 1, 1, 1, 0, dtFlag, 4096, 256, 2048, 0L, 1, 0L, 1, 0L);
  gemm_mfma<<<dim3(4, 64, 1), B, 0, stream>>>(
      rep, 1, Wmu, bmu, d_out, 2, 1, 0, 0, dtFlag, 4096, 256, 256, 0L, 1, 0L, 1, 0L);
}

// Round 8
// 782.737 us; speedup vs baseline: 5.9348x; 1.0904x over previous
//
#include <hip/hip_runtime.h>
#include <hip/hip_bf16.h>

typedef __hip_bfloat16 bf16;
typedef __attribute__((ext_vector_type(8))) short short8;
typedef __attribute__((ext_vector_type(4))) float f32x4;
typedef __attribute__((ext_vector_type(4))) unsigned short us4;
#define DEV __device__ __forceinline__

static constexpr int T_ = 8, NC = 512, NT = 512, D_ = 256, H_ = 8, NBF = 1419;
static constexpr int FP = 1472;             // padded F (23*64 = 46*32), zero tail
static constexpr float EPS_ = 1e-4f;
static constexpr float DN = 0.25f;          // D^-0.25
static constexpr float DIAG_SC = 0.03125f;  // 0.5 * DN^2

DEV float bf2f(unsigned short u) { return __uint_as_float(((unsigned)u) << 16); }
DEV float tofloat(bf16 x) { return __bfloat162float(x); }
DEV unsigned short f2bu(float x) { bf16 h = __float2bfloat16(x); return *(unsigned short*)&h; }

DEV float ldx(const void* p, long i, int isb) {
  if (isb) return bf2f(((const unsigned short*)p)[i]);
  return ((const float*)p)[i];
}
DEV void stx(void* p, long i, float v, int isb) {
  if (isb) ((bf16*)p)[i] = __float2bfloat16(v);
  else     ((float*)p)[i] = v;
}
DEV void unpack8(uint4 u, float* dst) {
  unsigned w[4] = {u.x, u.y, u.z, u.w};
#pragma unroll
  for (int i = 0; i < 4; i++) {
    dst[2 * i + 0] = __uint_as_float((w[i] & 0xffffu) << 16);
    dst[2 * i + 1] = __uint_as_float(w[i] & 0xffff0000u);
  }
}

// ------------------------------------------------------------------
// dtype probe (1 = bf16 inputs, 0 = fp32)
// ------------------------------------------------------------------
__global__ __launch_bounds__(256)
void detect_dtype(const void* __restrict__ x, int* __restrict__ flag)
{
  __shared__ int bad;
  if (threadIdx.x == 0) bad = 0;
  __syncthreads();
  int mybad = 0;
  for (int j = 0; j < 16; j++) {
    long i = 2L * (threadIdx.x + 256L * j);
    unsigned short u = ((const unsigned short*)x)[i];
    int e = (u >> 7) & 0xff, mant = u & 0x7f;
    bool b = (e == 0xff) || (e >= 141) || (e <= 93 && !(e == 0 && mant == 0));
    mybad += b ? 1 : 0;
  }
  atomicAdd(&bad, mybad);
  __syncthreads();
  if (threadIdx.x == 0) *flag = (bad > 1024) ? 0 : 1;
}

// proj -> bf16 [FP][256], zero rows past NBF
__global__ __launch_bounds__(256)
void conv_proj(const void* __restrict__ proj, bf16* __restrict__ projB,
               const int* __restrict__ dtFlag)
{
  const int fl = *dtFlag;
  int f = blockIdx.x, t = threadIdx.x;
  float v = (f < NBF) ? ldx(proj, (long)f * 256 + t, fl) : 0.f;
  projB[(long)f * 256 + t] = __float2bfloat16(v);
}

// ------------------------------------------------------------------
// MFMA GEMM (unchanged from round 7).
// ------------------------------------------------------------------
__global__ __launch_bounds__(256)
void gemm_mfma(const void* __restrict__ A, int aMode,
               const void* __restrict__ B, const void* __restrict__ bias,
               void* __restrict__ C, int cMode, int epi, int bPerm, int cT,
               const int* __restrict__ dtFlag,
               int M, int N, int K, long sA, int divA, long sB, int modB, long sBias)
{
  __shared__ bf16 As[64 * 40];
  __shared__ bf16 Ws[64 * 40];
  const int fl = *dtFlag;
  const int aB = (aMode == 2) ? fl : aMode;
  const int cB = (cMode == 2) ? fl : cMode;
  const int t = threadIdx.x;
  const int bz = blockIdx.z;
  const long aOff = (long)(bz / divA) * sA;
  const long bOff = (long)(bz % modB) * sB;
  const long biasOff = (long)(bz % modB) * sBias;
  const long cOff = (long)bz * (long)M * N;
  const int m0 = blockIdx.y * 64, n0 = blockIdx.x * 64;
  const int w = t >> 6, l = t & 63, quad = l >> 4, ln = l & 15;
  const int am = t >> 2, ak8 = (t & 3) * 8;
  const int wk = t & 31, wg = t >> 5;
  f32x4 acc[4] = {};

  for (int k0 = 0; k0 < K; k0 += 32) {
    if (aB == 1) {
      const uint4* src = (const uint4*)((const bf16*)A + aOff + (long)(m0 + am) * K + k0 + ak8);
      *(uint4*)(&As[am * 40 + ak8]) = *src;
    } else {
      const float* src = (const float*)A + aOff + (long)(m0 + am) * K + k0 + ak8;
      unsigned short tmp[8];
#pragma unroll
      for (int i = 0; i < 8; i++) tmp[i] = f2bu(src[i]);
      *(uint4*)(&As[am * 40 + ak8]) = *(const uint4*)tmp;
    }
    {
      int k = k0 + wk;
      int krow = bPerm ? (((k & 255) << 3) | (k >> 8)) : k;
      if (fl == 1) {
        uint4 u = *(const uint4*)((const bf16*)B + bOff + (long)krow * N + n0 + wg * 8);
        const unsigned short* us = (const unsigned short*)&u;
#pragma unroll
        for (int j = 0; j < 8; j++) Ws[(wg * 8 + j) * 40 + wk] = *(const bf16*)&us[j];
      } else {
        const float* src = (const float*)B + bOff + (long)krow * N + n0 + wg * 8;
#pragma unroll
        for (int j = 0; j < 8; j++) {
          unsigned short u = f2bu(src[j]);
          Ws[(wg * 8 + j) * 40 + wk] = *(const bf16*)&u;
        }
      }
    }
    __syncthreads();
    short8 a = *(const short8*)(&As[(16 * w + ln) * 40 + quad * 8]);
#pragma unroll
    for (int i = 0; i < 4; i++) {
      short8 b = *(const short8*)(&Ws[(16 * i + ln) * 40 + quad * 8]);
      acc[i] = __builtin_amdgcn_mfma_f32_16x16x32_bf16(a, b, acc[i], 0, 0, 0);
    }
    __syncthreads();
  }

#pragma unroll
  for (int i = 0; i < 4; i++) {
#pragma unroll
    for (int r = 0; r < 4; r++) {
      int m = m0 + 16 * w + quad * 4 + r;
      int n = n0 + 16 * i + ln;
      float c = acc[i][r];
      if (epi >= 1) c += ldx(bias, biasOff + n, fl);
      if (epi == 2) c = fmaxf(c, 0.f);
      long idx = cT ? (cOff + (long)n * M + m) : (cOff + (long)m * N + n);
      stx(C, idx, c, cB);
    }
  }
}

__global__ __launch_bounds__(256)
void fixup_h1(bf16* __restrict__ h1, const void* __restrict__ label,
              const void* __restrict__ W1, const void* __restrict__ b1,
              const int* __restrict__ dtFlag)
{
  const int fl = *dtFlag;
  int idx = blockIdx.x * 256 + threadIdx.x;
  int m = idx >> 8, n = idx & 255;
  float c = tofloat(h1[idx]) + ldx(b1, n, fl);
#pragma unroll
  for (int j = 0; j < 3; j++)
    c += ldx(label, m * 3 + j, fl) * ldx(W1, (256 + j) * 256 + n, fl);
  h1[idx] = __float2bfloat16(fmaxf(c, 0.f));
}

__global__ __launch_bounds__(64)
void diag_kernel(const bf16* __restrict__ X, float* __restrict__ diag)
{
  int r = blockIdx.x, lane = threadIdx.x;
  uint2 u = ((const uint2*)(X + (long)r * 256))[lane];
  float a = bf2f((unsigned short)(u.x & 0xffff)), b2 = bf2f((unsigned short)(u.x >> 16));
  float c = bf2f((unsigned short)(u.y & 0xffff)), d = bf2f((unsigned short)(u.y >> 16));
  float s = a * a + b2 * b2 + c * c + d * d;
#pragma unroll
  for (int off = 32; off > 0; off >>= 1) s += __shfl_down(s, off);
  if (lane == 0) diag[r] = DIAG_SC * s;
}

// ------------------------------------------------------------------
// Key-side fused v2: FT=64 per block (23 blocks/bz), proj frags in REGS
// (block-invariant, no projS LDS). Per n-chunk of 32:
//  Phase A: 4 indep MFMA chains (2 n-halves x split-K), E -> pS[f][n]
//  Phase B: 16 indep acc, ctx[f][e] += P^T @ v
// LDS ~42.7 KB -> ~3 blocks/CU.
// ------------------------------------------------------------------
__global__ __launch_bounds__(256)
void key_fused_mfma(const bf16* __restrict__ k, const bf16* __restrict__ vT,
                    const bf16* __restrict__ projB, const float* __restrict__ diagk,
                    float* __restrict__ ksumE, bf16* __restrict__ ctxT,
                    float* __restrict__ mpart)
{
  __shared__ bf16 kS[32 * 264];
  __shared__ bf16 vS[256 * 40];
  __shared__ bf16 pS[64 * 40];      // [64 f][32 n + pad]
  __shared__ float dS[32];
  __shared__ float wredM[4];

  const int bz = blockIdx.y, ft = blockIdx.x, f0 = ft * 64;
  const int t = threadIdx.x;
  const int w = t >> 6, l = t & 63, quad = l >> 4, ln = l & 15;
  const int fmine = f0 + 16 * w + ln;       // this lane's proj row (phase A B-op)
  const bool fv = fmine < NBF;

  // preload proj B-fragments for all 8 k-chunks (block-invariant)
  short8 pf[8];
  {
    const bf16* prow = projB + (long)fmine * 256;
#pragma unroll
    for (int kc = 0; kc < 8; kc++)
      pf[kc] = *(const short8*)(prow + kc * 32 + quad * 8);
  }
  const bf16* kb = k + (long)bz * NC * 256;
  const bf16* vtb = vT + (long)bz * 256 * NC;
  const float* db = diagk + bz * NC;

  f32x4 acc[4][4] = {};      // [fh][ei]: f = f0+16fh+quad*4+r, e = 64w+16ei+ln
  float ksumP = 0.f, mP = -1e30f;

  for (int n0 = 0; n0 < NC; n0 += 32) {
    {
      const int row = t >> 3, ch = (t & 7) * 32;
      const uint4* src = (const uint4*)(kb + (long)(n0 + row) * 256 + ch);
      uint4* dst = (uint4*)(&kS[row * 264 + ch]);
#pragma unroll
      for (int i = 0; i < 4; i++) dst[i] = src[i];
    }
    {
      const uint4* src = (const uint4*)(vtb + (long)t * NC + n0);
      uint4* dst = (uint4*)(&vS[t * 40]);
#pragma unroll
      for (int i = 0; i < 4; i++) dst[i] = src[i];
    }
    if (t < 32) dS[t] = db[n0 + t];
    __syncthreads();

    // phase A: dd tiles for n-halves mi=0,1; split-K into 2 chains each
    f32x4 dd[2][2] = {};
#pragma unroll
    for (int kc = 0; kc < 8; kc++) {
      const int hf = kc & 1;
#pragma unroll
      for (int mi = 0; mi < 2; mi++) {
        short8 a = *(const short8*)(&kS[(16 * mi + ln) * 264 + kc * 32 + quad * 8]);
        dd[mi][hf] = __builtin_amdgcn_mfma_f32_16x16x32_bf16(a, pf[kc], dd[mi][hf], 0, 0, 0);
      }
    }
#pragma unroll
    for (int mi = 0; mi < 2; mi++) {
      us4 ev;
#pragma unroll
      for (int r = 0; r < 4; r++) {
        float sc = DN * (dd[mi][0][r] + dd[mi][1][r]);
        float E = fv ? __expf(fminf(sc - dS[16 * mi + quad * 4 + r], 80.f)) : 0.f;
        unsigned short u = f2bu(E);
        ksumP += bf2f(u);
        if (fv) mP = fmaxf(mP, sc);
        ev[r] = u;
      }
      *(us4*)(&pS[(16 * w + ln) * 40 + 16 * mi + quad * 4]) = ev;
    }
    __syncthreads();

    // phase B: wave w covers e in [64w, 64w+64), all 4 f-quarters
    short8 bfr[4];
#pragma unroll
    for (int ei = 0; ei < 4; ei++)
      bfr[ei] = *(const short8*)(&vS[(64 * w + 16 * ei + ln) * 40 + quad * 8]);
#pragma unroll
    for (int fh = 0; fh < 4; fh++) {
      short8 a = *(const short8*)(&pS[(16 * fh + ln) * 40 + quad * 8]);
#pragma unroll
      for (int ei = 0; ei < 4; ei++)
        acc[fh][ei] = __builtin_amdgcn_mfma_f32_16x16x32_bf16(a, bfr[ei], acc[fh][ei], 0, 0, 0);
    }
    __syncthreads();
  }

  // ctxT stores: f-contiguous packs of 4
#pragma unroll
  for (int fh = 0; fh < 4; fh++) {
#pragma unroll
    for (int ei = 0; ei < 4; ei++) {
      int e = 64 * w + 16 * ei + ln;
      us4 cv;
#pragma unroll
      for (int r = 0; r < 4; r++) cv[r] = f2bu(acc[fh][ei][r]);
      *(us4*)(&ctxT[((long)bz * 256 + e) * FP + f0 + 16 * fh + quad * 4]) = cv;
    }
  }

  // ksum: lane holds partials for f=fmine over n subset; reduce over quads
  float s = ksumP;
  s += __shfl_xor(s, 16); s += __shfl_xor(s, 32);
  if (quad == 0 && fv) ksumE[(long)bz * NBF + fmine] = s;
  // block max of dd (valid f only)
  float m = mP;
#pragma unroll
  for (int off = 1; off < 64; off <<= 1) m = fmaxf(m, __shfl_xor(m, off));
  if (l == 0) wredM[w] = m;
  __syncthreads();
  if (t == 0)
    mpart[bz * 23 + ft] = fmaxf(fmaxf(wredM[0], wredM[1]), fmaxf(wredM[2], wredM[3]));
}

__global__ __launch_bounds__(64)
void mk_reduce(const float* __restrict__ mpart, float* __restrict__ mk)
{
  int bz = blockIdx.x, l = threadIdx.x;
  float m = (l < 23) ? mpart[bz * 23 + l] : -1e30f;
#pragma unroll
  for (int off = 32; off > 0; off >>= 1) m = fmaxf(m, __shfl_down(m, off));
  if (l == 0) mk[bz] = m;
}

__global__ __launch_bounds__(256)
void sv_kernel_T(const bf16* __restrict__ vT, float* __restrict__ Sv)
{
  int bz = blockIdx.x, e = threadIdx.x;
  const uint4* r4 = (const uint4*)(vT + ((long)bz * 256 + e) * NC);
  float s = 0.f;
  for (int i = 0; i < 64; i++) {
    float tmp[8];
    unpack8(r4[i], tmp);
#pragma unroll
    for (int j = 0; j < 8; j++) s += tmp[j];
  }
  Sv[bz * 256 + e] = s;
}

__global__ __launch_bounds__(256)
void ctx_finT(bf16* __restrict__ ctxT, const float* __restrict__ Sv,
              const float* __restrict__ mk)
{
  int e = blockIdx.x, bz = blockIdx.y, t = threadIdx.x;
  float emk = __expf(-mk[bz]);
  float sve = EPS_ * Sv[bz * 256 + e];
  bf16* row = ctxT + ((long)bz * 256 + e) * FP;
  for (int f = t; f < FP; f += 256) {
    float val = (f < NBF) ? (emk * tofloat(row[f]) + sve) : 0.f;
    row[f] = __float2bfloat16(val);
  }
}

__global__ __launch_bounds__(256)
void ksum_fin(float* __restrict__ ksumE, const float* __restrict__ mk,
              float* __restrict__ ksumtot)
{
  __shared__ float red[4];
  int bz = blockIdx.x, t = threadIdx.x;
  float emk = __expf(-mk[bz]);
  float s = 0.f;
  for (int f = t; f < NBF; f += 256) {
    float kf = emk * ksumE[(long)bz * NBF + f] + (float)NC * EPS_;
    ksumE[(long)bz * NBF + f] = kf;
    s += kf;
  }
#pragma unroll
  for (int off = 32; off > 0; off >>= 1) s += __shfl_down(s, off);
  if ((t & 63) == 0) red[t >> 6] = s;
  __syncthreads();
  if (t == 0) ksumtot[bz] = red[0] + red[1] + red[2] + red[3];
}

__global__ __launch_bounds__(256)
void ctxsumT_k(const bf16* __restrict__ ctxT, float* __restrict__ ctxsum)
{
  int bz = blockIdx.x, e = threadIdx.x;
  const bf16* row = ctxT + ((long)bz * 256 + e) * FP;
  const uint4* r4 = (const uint4*)row;
  float s = 0.f;
  for (int i = 0; i < FP / 8; i++) {   // tail is zeroed
    float tmp[8];
    unpack8(r4[i], tmp);
#pragma unroll
    for (int j = 0; j < 8; j++) s += tmp[j];
  }
  ctxsum[bz * 256 + e] = s;
}

// ------------------------------------------------------------------
// Query-side fused, MFMA. 46 f-tiles; split dd chains. merged [t][n][h][e].
// ------------------------------------------------------------------
__global__ __launch_bounds__(256)
void q_fused_mfma(const bf16* __restrict__ q, const bf16* __restrict__ projB,
                  const float* __restrict__ diagq, const bf16* __restrict__ ctxT,
                  const float* __restrict__ ksum, const float* __restrict__ ctxsum,
                  const float* __restrict__ ksumtot, bf16* __restrict__ merged)
{
  __shared__ bf16 qS[32 * 264];
  __shared__ bf16 projS[32 * 264];
  __shared__ bf16 eS[32 * 40];
  __shared__ bf16 ctxTs[256 * 40];
  __shared__ float ksumS[32];
  __shared__ float dS[32];
  __shared__ float csS[256];
  __shared__ float sS[32][2];
  __shared__ float mS[32][2];

  const int bz = blockIdx.y, nt = blockIdx.x, t = threadIdx.x;
  const int w = t >> 6, l = t & 63, quad = l >> 4, ln = l & 15;
  const int mi = w & 1, fi = w >> 1;
  const int tq = bz / H_, hh = bz % H_;

  {
    const int row = t >> 3, ch = (t & 7) * 32;
    const uint4* src = (const uint4*)(q + ((long)bz * NT + nt * 32 + row) * 256 + ch);
    uint4* dst = (uint4*)(&qS[row * 264 + ch]);
#pragma unroll
    for (int i = 0; i < 4; i++) dst[i] = src[i];
  }
  if (t < 32) dS[t] = diagq[(long)bz * NT + nt * 32 + t];
  csS[t] = ctxsum[bz * 256 + t];

  f32x4 acc[2][4] = {};
  float sPart[4] = {0.f, 0.f, 0.f, 0.f};
  float mPart[4] = {0.f, 0.f, 0.f, 0.f};
  __syncthreads();

  for (int ft = 0; ft < FP / 32; ft++) {
    const int f0 = ft * 32;
    {
      const int row = t >> 3, ch = (t & 7) * 32;
      const uint4* src = (const uint4*)(projB + (long)(f0 + row) * 256 + ch);
      uint4* dst = (uint4*)(&projS[row * 264 + ch]);
#pragma unroll
      for (int i = 0; i < 4; i++) dst[i] = src[i];
    }
    {
      const uint4* src = (const uint4*)(ctxT + ((long)bz * 256 + t) * FP + f0);
      uint4* dst = (uint4*)(&ctxTs[t * 40]);
#pragma unroll
      for (int i = 0; i < 4; i++) dst[i] = src[i];
    }
    if (t < 32) ksumS[t] = (f0 + t < NBF) ? ksum[(long)bz * NBF + f0 + t] : 0.f;
    __syncthreads();

    f32x4 dd0 = {}, dd1 = {};
#pragma unroll
    for (int kc = 0; kc < 8; kc += 2) {
      short8 a0 = *(const short8*)(&qS[(16 * mi + ln) * 264 + kc * 32 + quad * 8]);
      short8 b0 = *(const short8*)(&projS[(16 * fi + ln) * 264 + kc * 32 + quad * 8]);
      dd0 = __builtin_amdgcn_mfma_f32_16x16x32_bf16(a0, b0, dd0, 0, 0, 0);
      short8 a1 = *(const short8*)(&qS[(16 * mi + ln) * 264 + (kc + 1) * 32 + quad * 8]);
      short8 b1 = *(const short8*)(&projS[(16 * fi + ln) * 264 + (kc + 1) * 32 + quad * 8]);
      dd1 = __builtin_amdgcn_mfma_f32_16x16x32_bf16(a1, b1, dd1, 0, 0, 0);
    }
    const bool fv = (f0 + 16 * fi + ln) < NBF;
    const float kv = ksumS[16 * fi + ln];
#pragma unroll
    for (int r = 0; r < 4; r++) {
      float E = fv ? __expf(fminf(DN * (dd0[r] + dd1[r]), 80.f)) : 0.f;
      bf16 h = __float2bfloat16(E);
      float Er = tofloat(h);
      eS[(16 * mi + quad * 4 + r) * 40 + 16 * fi + ln] = h;
      sPart[r] += Er * kv;
      mPart[r] = fmaxf(mPart[r], Er);
    }
    __syncthreads();

#pragma unroll
    for (int mh = 0; mh < 2; mh++) {
      short8 a = *(const short8*)(&eS[(16 * mh + ln) * 40 + quad * 8]);
#pragma unroll
      for (int i = 0; i < 4; i++) {
        short8 b = *(const short8*)(&ctxTs[(16 * (4 * w + i) + ln) * 40 + quad * 8]);
        acc[mh][i] = __builtin_amdgcn_mfma_f32_16x16x32_bf16(a, b, acc[mh][i], 0, 0, 0);
      }
    }
    __syncthreads();
  }

#pragma unroll
  for (int r = 0; r < 4; r++) {
    float s = sPart[r], m = mPart[r];
#pragma unroll
    for (int off = 1; off < 16; off <<= 1) {
      s += __shfl_xor(s, off);
      m = fmaxf(m, __shfl_xor(m, off));
    }
    if (ln == 0) {
      sS[16 * mi + quad * 4 + r][fi] = s;
      mS[16 * mi + quad * 4 + r][fi] = m;
    }
  }
  __syncthreads();

  const float ktotv = ksumtot[bz];
#pragma unroll
  for (int mh = 0; mh < 2; mh++) {
#pragma unroll
    for (int r = 0; r < 4; r++) {
      int row = 16 * mh + quad * 4 + r;
      float st = sS[row][0] + sS[row][1];
      float mt = fmaxf(fmaxf(mS[row][0], mS[row][1]), 1e-30f);
      float c = __expf(-dS[row]) / mt;
      float inv = 1.f / (c * st + EPS_ * ktotv);
#pragma unroll
      for (int i = 0; i < 4; i++) {
        int e = 16 * (4 * w + i) + ln;
        float val = (c * acc[mh][i][r] + EPS_ * csS[e]) * inv;
        merged[((long)tq * NT + nt * 32 + row) * 2048 + hh * 256 + e] =
            __float2bfloat16(val);
      }
    }
  }
}

// ------------------------------------------------------------------
extern "C" void kernel_launch(void* const* d_in, const int* in_sizes, int n_in,
                              void* d_out, int out_size, void* d_ws, size_t ws_size,
                              hipStream_t stream)
{
  const void* x_ctx = d_in[0];
  const void* label = d_in[1];
  const void* x_tgt = d_in[2];
  const void* W1 = d_in[3];
  const void* b1 = d_in[4];
  const void* W2 = d_in[5];
  const void* b2 = d_in[6];
  const void* W3 = d_in[7];
  const void* b3 = d_in[8];
  const void* Wk = d_in[9];
  const void* bk = d_in[10];
  const void* Wv = d_in[11];
  const void* bv = d_in[12];
  const void* Wq = d_in[13];
  const void* bq = d_in[14];
  const void* Wo = d_in[15];
  const void* bo = d_in[16];
  const void* Wmu = d_in[17];
  const void* bmu = d_in[18];
  const void* proj = d_in[19];

  // Arena (floats), peak ~84 MB
  float* W = (float*)d_ws;
  const long F0 = 0, F1 = 4194304, F2 = 8388608;
  const long CTXT_F = (long)64 * 256 * FP / 2;   // 12,058,624 floats
  const long F3 = F2 + CTXT_F;
  bf16* kB = (bf16*)(W + F0);
  bf16* qB = (bf16*)(W + F0);
  bf16* rep = (bf16*)(W + F0);
  bf16* vT = (bf16*)(W + F1);
  bf16* merged = (bf16*)(W + F1);
  bf16* h1 = (bf16*)(W + F2);
  bf16* h2 = (bf16*)(W + F2 + 524288);
  bf16* cf = (bf16*)(W + F2 + 1048576);
  bf16* ctxT = (bf16*)(W + F2);
  long o = F3;
  auto alloc = [&](long n) { float* p = W + o; o += n; return p; };
  float* dgk = alloc(32768);
  float* dgq = alloc(32768);
  float* ksumE = alloc((long)64 * NBF);
  float* mpart = alloc(64 * 23);
  float* mk = alloc(64);
  float* Sv = alloc(64 * 256);
  float* ctxs = alloc(64 * 256);
  float* ktot = alloc(64);
  int* dtFlag = (int*)alloc(64);
  bf16* projB = (bf16*)alloc((long)FP * 256 / 2);
  (void)ws_size; (void)in_sizes; (void)n_in; (void)out_size;

  const dim3 B(256);
  detect_dtype<<<1, B, 0, stream>>>(x_ctx, dtFlag);
  conv_proj<<<FP, B, 0, stream>>>(proj, projB, dtFlag);
  // 1. task-encoder MLP (bf16 activations)
  gemm_mfma<<<dim3(4, 64, 1), B, 0, stream>>>(
      x_ctx, 2, W1, nullptr, h1, 1, 0, 0, 0, dtFlag, 4096, 256, 256, 0L, 1, 0L, 1, 0L);
  fixup_h1<<<4096, B, 0, stream>>>(h1, label, W1, b1, dtFlag);
  gemm_mfma<<<dim3(4, 64, 1), B, 0, stream>>>(
      h1, 1, W2, b2, h2, 1, 2, 0, 0, dtFlag, 4096, 256, 256, 0L, 1, 0L, 1, 0L);
  gemm_mfma<<<dim3(4, 64, 1), B, 0, stream>>>(
      h2, 1, W3, b3, cf, 1, 2, 0, 0, dtFlag, 4096, 256, 256, 0L, 1, 0L, 1, 0L);
  // 2. k projection (natural), v projection (transposed -> vT)
  gemm_mfma<<<dim3(4, 8, 64), B, 0, stream>>>(
      x_ctx, 2, Wk, bk, kB, 1, 1, 0, 0, dtFlag, 512, 256, 256, (long)512 * 256, H_, 65536L, H_, 256L);
  gemm_mfma<<<dim3(4, 8, 64), B, 0, stream>>>(
      cf, 1, Wv, bv, vT, 1, 1, 0, 1, dtFlag, 512, 256, 256, (long)512 * 256, H_, 65536L, H_, 256L);
  // 3. key side (MFMA v2, FT=64)
  diag_kernel<<<32768, 64, 0, stream>>>(kB, dgk);
  key_fused_mfma<<<dim3(23, 64), B, 0, stream>>>(kB, vT, projB, dgk, ksumE, ctxT, mpart);
  mk_reduce<<<64, 64, 0, stream>>>(mpart, mk);
  sv_kernel_T<<<64, B, 0, stream>>>(vT, Sv);
  ctx_finT<<<dim3(256, 64), B, 0, stream>>>(ctxT, Sv, mk);
  ksum_fin<<<64, B, 0, stream>>>(ksumE, mk, ktot);
  ctxsumT_k<<<64, B, 0, stream>>>(ctxT, ctxs);
  // 4. q projection + diag
  gemm_mfma<<<dim3(4, 8, 64), B, 0, stream>>>(
      x_tgt, 2, Wq, bq, qB, 1, 1, 0, 0, dtFlag, 512, 256, 256, (long)512 * 256, H_, 65536L, H_, 256L);
  diag_kernel<<<32768, 64, 0, stream>>>(qB, dgq);
  // 5. query side (MFMA) -> merged [t][n][h][e]
  q_fused_mfma<<<dim3(16, 64), B, 0, stream>>>(qB, projB, dgq, ctxT, ksumE, ctxs, ktot, merged);
  // 6. output projections (Wo rows permuted: k=h*256+e -> logical e*8+h)
  gemm_mfma<<<dim3(4, 64, 1), B, 0, stream>>>(
      merged, 1, Wo, bo, rep, 1, 1, 1, 0, dtFlag, 4096, 256, 2048, 0L, 1, 0L, 1, 0L);
  gemm_mfma<<<dim3(4, 64, 1), B, 0, stream>>>(
      rep, 1, Wmu, bmu, d_out, 2, 1, 0, 0, dtFlag, 4096, 256, 256, 0L, 1, 0L, 1, 0L);
}

// Round 9
// 768.793 us; speedup vs baseline: 6.0424x; 1.0181x over previous
//
#include <hip/hip_runtime.h>
#include <hip/hip_bf16.h>

typedef __hip_bfloat16 bf16;
typedef __attribute__((ext_vector_type(8))) short short8;
typedef __attribute__((ext_vector_type(4))) float f32x4;
typedef __attribute__((ext_vector_type(4))) unsigned short us4;
#define DEV __device__ __forceinline__

static constexpr int T_ = 8, NC = 512, NT = 512, D_ = 256, H_ = 8, NBF = 1419;
static constexpr int FP = 1472;             // padded F (23*64 = 46*32), zero tail
static constexpr float EPS_ = 1e-4f;
static constexpr float DN = 0.25f;          // D^-0.25
static constexpr float DIAG_SC = 0.03125f;  // 0.5 * DN^2

DEV float bf2f(unsigned short u) { return __uint_as_float(((unsigned)u) << 16); }
DEV float tofloat(bf16 x) { return __bfloat162float(x); }
DEV unsigned short f2bu(float x) { bf16 h = __float2bfloat16(x); return *(unsigned short*)&h; }

DEV float ldx(const void* p, long i, int isb) {
  if (isb) return bf2f(((const unsigned short*)p)[i]);
  return ((const float*)p)[i];
}
DEV void stx(void* p, long i, float v, int isb) {
  if (isb) ((bf16*)p)[i] = __float2bfloat16(v);
  else     ((float*)p)[i] = v;
}
DEV void unpack8(uint4 u, float* dst) {
  unsigned w[4] = {u.x, u.y, u.z, u.w};
#pragma unroll
  for (int i = 0; i < 4; i++) {
    dst[2 * i + 0] = __uint_as_float((w[i] & 0xffffu) << 16);
    dst[2 * i + 1] = __uint_as_float(w[i] & 0xffff0000u);
  }
}

// ------------------------------------------------------------------
// dtype probe (1 = bf16 inputs, 0 = fp32)
// ------------------------------------------------------------------
__global__ __launch_bounds__(256)
void detect_dtype(const void* __restrict__ x, int* __restrict__ flag)
{
  __shared__ int bad;
  if (threadIdx.x == 0) bad = 0;
  __syncthreads();
  int mybad = 0;
  for (int j = 0; j < 16; j++) {
    long i = 2L * (threadIdx.x + 256L * j);
    unsigned short u = ((const unsigned short*)x)[i];
    int e = (u >> 7) & 0xff, mant = u & 0x7f;
    bool b = (e == 0xff) || (e >= 141) || (e <= 93 && !(e == 0 && mant == 0));
    mybad += b ? 1 : 0;
  }
  atomicAdd(&bad, mybad);
  __syncthreads();
  if (threadIdx.x == 0) *flag = (bad > 1024) ? 0 : 1;
}

// proj -> bf16 [FP][256], zero rows past NBF
__global__ __launch_bounds__(256)
void conv_proj(const void* __restrict__ proj, bf16* __restrict__ projB,
               const int* __restrict__ dtFlag)
{
  const int fl = *dtFlag;
  int f = blockIdx.x, t = threadIdx.x;
  float v = (f < NBF) ? ldx(proj, (long)f * 256 + t, fl) : 0.f;
  projB[(long)f * 256 + t] = __float2bfloat16(v);
}

// ------------------------------------------------------------------
// MFMA GEMM (unchanged).
// ------------------------------------------------------------------
__global__ __launch_bounds__(256)
void gemm_mfma(const void* __restrict__ A, int aMode,
               const void* __restrict__ B, const void* __restrict__ bias,
               void* __restrict__ C, int cMode, int epi, int bPerm, int cT,
               const int* __restrict__ dtFlag,
               int M, int N, int K, long sA, int divA, long sB, int modB, long sBias)
{
  __shared__ bf16 As[64 * 40];
  __shared__ bf16 Ws[64 * 40];
  const int fl = *dtFlag;
  const int aB = (aMode == 2) ? fl : aMode;
  const int cB = (cMode == 2) ? fl : cMode;
  const int t = threadIdx.x;
  const int bz = blockIdx.z;
  const long aOff = (long)(bz / divA) * sA;
  const long bOff = (long)(bz % modB) * sB;
  const long biasOff = (long)(bz % modB) * sBias;
  const long cOff = (long)bz * (long)M * N;
  const int m0 = blockIdx.y * 64, n0 = blockIdx.x * 64;
  const int w = t >> 6, l = t & 63, quad = l >> 4, ln = l & 15;
  const int am = t >> 2, ak8 = (t & 3) * 8;
  const int wk = t & 31, wg = t >> 5;
  f32x4 acc[4] = {};

  for (int k0 = 0; k0 < K; k0 += 32) {
    if (aB == 1) {
      const uint4* src = (const uint4*)((const bf16*)A + aOff + (long)(m0 + am) * K + k0 + ak8);
      *(uint4*)(&As[am * 40 + ak8]) = *src;
    } else {
      const float* src = (const float*)A + aOff + (long)(m0 + am) * K + k0 + ak8;
      unsigned short tmp[8];
#pragma unroll
      for (int i = 0; i < 8; i++) tmp[i] = f2bu(src[i]);
      *(uint4*)(&As[am * 40 + ak8]) = *(const uint4*)tmp;
    }
    {
      int k = k0 + wk;
      int krow = bPerm ? (((k & 255) << 3) | (k >> 8)) : k;
      if (fl == 1) {
        uint4 u = *(const uint4*)((const bf16*)B + bOff + (long)krow * N + n0 + wg * 8);
        const unsigned short* us = (const unsigned short*)&u;
#pragma unroll
        for (int j = 0; j < 8; j++) Ws[(wg * 8 + j) * 40 + wk] = *(const bf16*)&us[j];
      } else {
        const float* src = (const float*)B + bOff + (long)krow * N + n0 + wg * 8;
#pragma unroll
        for (int j = 0; j < 8; j++) {
          unsigned short u = f2bu(src[j]);
          Ws[(wg * 8 + j) * 40 + wk] = *(const bf16*)&u;
        }
      }
    }
    __syncthreads();
    short8 a = *(const short8*)(&As[(16 * w + ln) * 40 + quad * 8]);
#pragma unroll
    for (int i = 0; i < 4; i++) {
      short8 b = *(const short8*)(&Ws[(16 * i + ln) * 40 + quad * 8]);
      acc[i] = __builtin_amdgcn_mfma_f32_16x16x32_bf16(a, b, acc[i], 0, 0, 0);
    }
    __syncthreads();
  }

#pragma unroll
  for (int i = 0; i < 4; i++) {
#pragma unroll
    for (int r = 0; r < 4; r++) {
      int m = m0 + 16 * w + quad * 4 + r;
      int n = n0 + 16 * i + ln;
      float c = acc[i][r];
      if (epi >= 1) c += ldx(bias, biasOff + n, fl);
      if (epi == 2) c = fmaxf(c, 0.f);
      long idx = cT ? (cOff + (long)n * M + m) : (cOff + (long)m * N + n);
      stx(C, idx, c, cB);
    }
  }
}

__global__ __launch_bounds__(256)
void fixup_h1(bf16* __restrict__ h1, const void* __restrict__ label,
              const void* __restrict__ W1, const void* __restrict__ b1,
              const int* __restrict__ dtFlag)
{
  const int fl = *dtFlag;
  int idx = blockIdx.x * 256 + threadIdx.x;
  int m = idx >> 8, n = idx & 255;
  float c = tofloat(h1[idx]) + ldx(b1, n, fl);
#pragma unroll
  for (int j = 0; j < 3; j++)
    c += ldx(label, m * 3 + j, fl) * ldx(W1, (256 + j) * 256 + n, fl);
  h1[idx] = __float2bfloat16(fmaxf(c, 0.f));
}

__global__ __launch_bounds__(64)
void diag_kernel(const bf16* __restrict__ X, float* __restrict__ diag)
{
  int r = blockIdx.x, lane = threadIdx.x;
  uint2 u = ((const uint2*)(X + (long)r * 256))[lane];
  float a = bf2f((unsigned short)(u.x & 0xffff)), b2 = bf2f((unsigned short)(u.x >> 16));
  float c = bf2f((unsigned short)(u.y & 0xffff)), d = bf2f((unsigned short)(u.y >> 16));
  float s = a * a + b2 * b2 + c * c + d * d;
#pragma unroll
  for (int off = 32; off > 0; off >>= 1) s += __shfl_down(s, off);
  if (lane == 0) diag[r] = DIAG_SC * s;
}

// ------------------------------------------------------------------
// Key-side fused v2 + XCD swizzle: grid (bz=64 on X, ft=23 on Y) so all
// ft-blocks of a bz share one XCD L2 (flat%8 = bz%8) -> k/vT fetched ~once.
// ------------------------------------------------------------------
__global__ __launch_bounds__(256)
void key_fused_mfma(const bf16* __restrict__ k, const bf16* __restrict__ vT,
                    const bf16* __restrict__ projB, const float* __restrict__ diagk,
                    float* __restrict__ ksumE, bf16* __restrict__ ctxT,
                    float* __restrict__ mpart)
{
  __shared__ bf16 kS[32 * 264];
  __shared__ bf16 vS[256 * 40];
  __shared__ bf16 pS[64 * 40];
  __shared__ float dS[32];
  __shared__ float wredM[4];

  const int bz = blockIdx.x, ft = blockIdx.y, f0 = ft * 64;   // XCD swizzle
  const int t = threadIdx.x;
  const int w = t >> 6, l = t & 63, quad = l >> 4, ln = l & 15;
  const int fmine = f0 + 16 * w + ln;
  const bool fv = fmine < NBF;

  short8 pf[8];
  {
    const bf16* prow = projB + (long)fmine * 256;
#pragma unroll
    for (int kc = 0; kc < 8; kc++)
      pf[kc] = *(const short8*)(prow + kc * 32 + quad * 8);
  }
  const bf16* kb = k + (long)bz * NC * 256;
  const bf16* vtb = vT + (long)bz * 256 * NC;
  const float* db = diagk + bz * NC;

  f32x4 acc[4][4] = {};
  float ksumP = 0.f, mP = -1e30f;

  for (int n0 = 0; n0 < NC; n0 += 32) {
    {
      const int row = t >> 3, ch = (t & 7) * 32;
      const uint4* src = (const uint4*)(kb + (long)(n0 + row) * 256 + ch);
      uint4* dst = (uint4*)(&kS[row * 264 + ch]);
#pragma unroll
      for (int i = 0; i < 4; i++) dst[i] = src[i];
    }
    {
      const uint4* src = (const uint4*)(vtb + (long)t * NC + n0);
      uint4* dst = (uint4*)(&vS[t * 40]);
#pragma unroll
      for (int i = 0; i < 4; i++) dst[i] = src[i];
    }
    if (t < 32) dS[t] = db[n0 + t];
    __syncthreads();

    f32x4 dd[2][2] = {};
#pragma unroll
    for (int kc = 0; kc < 8; kc++) {
      const int hf = kc & 1;
#pragma unroll
      for (int mi = 0; mi < 2; mi++) {
        short8 a = *(const short8*)(&kS[(16 * mi + ln) * 264 + kc * 32 + quad * 8]);
        dd[mi][hf] = __builtin_amdgcn_mfma_f32_16x16x32_bf16(a, pf[kc], dd[mi][hf], 0, 0, 0);
      }
    }
#pragma unroll
    for (int mi = 0; mi < 2; mi++) {
      us4 ev;
#pragma unroll
      for (int r = 0; r < 4; r++) {
        float sc = DN * (dd[mi][0][r] + dd[mi][1][r]);
        float E = fv ? __expf(fminf(sc - dS[16 * mi + quad * 4 + r], 80.f)) : 0.f;
        unsigned short u = f2bu(E);
        ksumP += bf2f(u);
        if (fv) mP = fmaxf(mP, sc);
        ev[r] = u;
      }
      *(us4*)(&pS[(16 * w + ln) * 40 + 16 * mi + quad * 4]) = ev;
    }
    __syncthreads();

    short8 bfr[4];
#pragma unroll
    for (int ei = 0; ei < 4; ei++)
      bfr[ei] = *(const short8*)(&vS[(64 * w + 16 * ei + ln) * 40 + quad * 8]);
#pragma unroll
    for (int fh = 0; fh < 4; fh++) {
      short8 a = *(const short8*)(&pS[(16 * fh + ln) * 40 + quad * 8]);
#pragma unroll
      for (int ei = 0; ei < 4; ei++)
        acc[fh][ei] = __builtin_amdgcn_mfma_f32_16x16x32_bf16(a, bfr[ei], acc[fh][ei], 0, 0, 0);
    }
    __syncthreads();
  }

#pragma unroll
  for (int fh = 0; fh < 4; fh++) {
#pragma unroll
    for (int ei = 0; ei < 4; ei++) {
      int e = 64 * w + 16 * ei + ln;
      us4 cv;
#pragma unroll
      for (int r = 0; r < 4; r++) cv[r] = f2bu(acc[fh][ei][r]);
      *(us4*)(&ctxT[((long)bz * 256 + e) * FP + f0 + 16 * fh + quad * 4]) = cv;
    }
  }

  float s = ksumP;
  s += __shfl_xor(s, 16); s += __shfl_xor(s, 32);
  if (quad == 0 && fv) ksumE[(long)bz * NBF + fmine] = s;
  float m = mP;
#pragma unroll
  for (int off = 1; off < 64; off <<= 1) m = fmaxf(m, __shfl_xor(m, off));
  if (l == 0) wredM[w] = m;
  __syncthreads();
  if (t == 0)
    mpart[bz * 23 + ft] = fmaxf(fmaxf(wredM[0], wredM[1]), fmaxf(wredM[2], wredM[3]));
}

__global__ __launch_bounds__(64)
void mk_reduce(const float* __restrict__ mpart, float* __restrict__ mk)
{
  int bz = blockIdx.x, l = threadIdx.x;
  float m = (l < 23) ? mpart[bz * 23 + l] : -1e30f;
#pragma unroll
  for (int off = 32; off > 0; off >>= 1) m = fmaxf(m, __shfl_down(m, off));
  if (l == 0) mk[bz] = m;
}

__global__ __launch_bounds__(256)
void sv_kernel_T(const bf16* __restrict__ vT, float* __restrict__ Sv)
{
  int bz = blockIdx.x, e = threadIdx.x;
  const uint4* r4 = (const uint4*)(vT + ((long)bz * 256 + e) * NC);
  float s = 0.f;
  for (int i = 0; i < 64; i++) {
    float tmp[8];
    unpack8(r4[i], tmp);
#pragma unroll
    for (int j = 0; j < 8; j++) s += tmp[j];
  }
  Sv[bz * 256 + e] = s;
}

__global__ __launch_bounds__(256)
void ctx_finT(bf16* __restrict__ ctxT, const float* __restrict__ Sv,
              const float* __restrict__ mk)
{
  int e = blockIdx.x, bz = blockIdx.y, t = threadIdx.x;
  float emk = __expf(-mk[bz]);
  float sve = EPS_ * Sv[bz * 256 + e];
  bf16* row = ctxT + ((long)bz * 256 + e) * FP;
  for (int f = t; f < FP; f += 256) {
    float val = (f < NBF) ? (emk * tofloat(row[f]) + sve) : 0.f;
    row[f] = __float2bfloat16(val);
  }
}

__global__ __launch_bounds__(256)
void ksum_fin(float* __restrict__ ksumE, const float* __restrict__ mk,
              float* __restrict__ ksumtot)
{
  __shared__ float red[4];
  int bz = blockIdx.x, t = threadIdx.x;
  float emk = __expf(-mk[bz]);
  float s = 0.f;
  for (int f = t; f < NBF; f += 256) {
    float kf = emk * ksumE[(long)bz * NBF + f] + (float)NC * EPS_;
    ksumE[(long)bz * NBF + f] = kf;
    s += kf;
  }
#pragma unroll
  for (int off = 32; off > 0; off >>= 1) s += __shfl_down(s, off);
  if ((t & 63) == 0) red[t >> 6] = s;
  __syncthreads();
  if (t == 0) ksumtot[bz] = red[0] + red[1] + red[2] + red[3];
}

__global__ __launch_bounds__(256)
void ctxsumT_k(const bf16* __restrict__ ctxT, float* __restrict__ ctxsum)
{
  int bz = blockIdx.x, e = threadIdx.x;
  const bf16* row = ctxT + ((long)bz * 256 + e) * FP;
  const uint4* r4 = (const uint4*)row;
  float s = 0.f;
  for (int i = 0; i < FP / 8; i++) {
    float tmp[8];
    unpack8(r4[i], tmp);
#pragma unroll
    for (int j = 0; j < 8; j++) s += tmp[j];
  }
  ctxsum[bz * 256 + e] = s;
}

// ------------------------------------------------------------------
// Query-side fused + XCD swizzle: grid (bz=64 on X, nt=16 on Y) so all
// nt-blocks of a bz share one XCD L2 -> ctxT fetched ~once per XCD.
// ------------------------------------------------------------------
__global__ __launch_bounds__(256)
void q_fused_mfma(const bf16* __restrict__ q, const bf16* __restrict__ projB,
                  const float* __restrict__ diagq, const bf16* __restrict__ ctxT,
                  const float* __restrict__ ksum, const float* __restrict__ ctxsum,
                  const float* __restrict__ ksumtot, bf16* __restrict__ merged)
{
  __shared__ bf16 qS[32 * 264];
  __shared__ bf16 projS[32 * 264];
  __shared__ bf16 eS[32 * 40];
  __shared__ bf16 ctxTs[256 * 40];
  __shared__ float ksumS[32];
  __shared__ float dS[32];
  __shared__ float csS[256];
  __shared__ float sS[32][2];
  __shared__ float mS[32][2];

  const int bz = blockIdx.x, nt = blockIdx.y, t = threadIdx.x;  // XCD swizzle
  const int w = t >> 6, l = t & 63, quad = l >> 4, ln = l & 15;
  const int mi = w & 1, fi = w >> 1;
  const int tq = bz / H_, hh = bz % H_;

  {
    const int row = t >> 3, ch = (t & 7) * 32;
    const uint4* src = (const uint4*)(q + ((long)bz * NT + nt * 32 + row) * 256 + ch);
    uint4* dst = (uint4*)(&qS[row * 264 + ch]);
#pragma unroll
    for (int i = 0; i < 4; i++) dst[i] = src[i];
  }
  if (t < 32) dS[t] = diagq[(long)bz * NT + nt * 32 + t];
  csS[t] = ctxsum[bz * 256 + t];

  f32x4 acc[2][4] = {};
  float sPart[4] = {0.f, 0.f, 0.f, 0.f};
  float mPart[4] = {0.f, 0.f, 0.f, 0.f};
  __syncthreads();

  for (int ft = 0; ft < FP / 32; ft++) {
    const int f0 = ft * 32;
    {
      const int row = t >> 3, ch = (t & 7) * 32;
      const uint4* src = (const uint4*)(projB + (long)(f0 + row) * 256 + ch);
      uint4* dst = (uint4*)(&projS[row * 264 + ch]);
#pragma unroll
      for (int i = 0; i < 4; i++) dst[i] = src[i];
    }
    {
      const uint4* src = (const uint4*)(ctxT + ((long)bz * 256 + t) * FP + f0);
      uint4* dst = (uint4*)(&ctxTs[t * 40]);
#pragma unroll
      for (int i = 0; i < 4; i++) dst[i] = src[i];
    }
    if (t < 32) ksumS[t] = (f0 + t < NBF) ? ksum[(long)bz * NBF + f0 + t] : 0.f;
    __syncthreads();

    f32x4 dd0 = {}, dd1 = {};
#pragma unroll
    for (int kc = 0; kc < 8; kc += 2) {
      short8 a0 = *(const short8*)(&qS[(16 * mi + ln) * 264 + kc * 32 + quad * 8]);
      short8 b0 = *(const short8*)(&projS[(16 * fi + ln) * 264 + kc * 32 + quad * 8]);
      dd0 = __builtin_amdgcn_mfma_f32_16x16x32_bf16(a0, b0, dd0, 0, 0, 0);
      short8 a1 = *(const short8*)(&qS[(16 * mi + ln) * 264 + (kc + 1) * 32 + quad * 8]);
      short8 b1 = *(const short8*)(&projS[(16 * fi + ln) * 264 + (kc + 1) * 32 + quad * 8]);
      dd1 = __builtin_amdgcn_mfma_f32_16x16x32_bf16(a1, b1, dd1, 0, 0, 0);
    }
    const bool fv = (f0 + 16 * fi + ln) < NBF;
    const float kv = ksumS[16 * fi + ln];
#pragma unroll
    for (int r = 0; r < 4; r++) {
      float E = fv ? __expf(fminf(DN * (dd0[r] + dd1[r]), 80.f)) : 0.f;
      bf16 h = __float2bfloat16(E);
      float Er = tofloat(h);
      eS[(16 * mi + quad * 4 + r) * 40 + 16 * fi + ln] = h;
      sPart[r] += Er * kv;
      mPart[r] = fmaxf(mPart[r], Er);
    }
    __syncthreads();

#pragma unroll
    for (int mh = 0; mh < 2; mh++) {
      short8 a = *(const short8*)(&eS[(16 * mh + ln) * 40 + quad * 8]);
#pragma unroll
      for (int i = 0; i < 4; i++) {
        short8 b = *(const short8*)(&ctxTs[(16 * (4 * w + i) + ln) * 40 + quad * 8]);
        acc[mh][i] = __builtin_amdgcn_mfma_f32_16x16x32_bf16(a, b, acc[mh][i], 0, 0, 0);
      }
    }
    __syncthreads();
  }

#pragma unroll
  for (int r = 0; r < 4; r++) {
    float s = sPart[r], m = mPart[r];
#pragma unroll
    for (int off = 1; off < 16; off <<= 1) {
      s += __shfl_xor(s, off);
      m = fmaxf(m, __shfl_xor(m, off));
    }
    if (ln == 0) {
      sS[16 * mi + quad * 4 + r][fi] = s;
      mS[16 * mi + quad * 4 + r][fi] = m;
    }
  }
  __syncthreads();

  const float ktotv = ksumtot[bz];
#pragma unroll
  for (int mh = 0; mh < 2; mh++) {
#pragma unroll
    for (int r = 0; r < 4; r++) {
      int row = 16 * mh + quad * 4 + r;
      float st = sS[row][0] + sS[row][1];
      float mt = fmaxf(fmaxf(mS[row][0], mS[row][1]), 1e-30f);
      float c = __expf(-dS[row]) / mt;
      float inv = 1.f / (c * st + EPS_ * ktotv);
#pragma unroll
      for (int i = 0; i < 4; i++) {
        int e = 16 * (4 * w + i) + ln;
        float val = (c * acc[mh][i][r] + EPS_ * csS[e]) * inv;
        merged[((long)tq * NT + nt * 32 + row) * 2048 + hh * 256 + e] =
            __float2bfloat16(val);
      }
    }
  }
}

// ------------------------------------------------------------------
extern "C" void kernel_launch(void* const* d_in, const int* in_sizes, int n_in,
                              void* d_out, int out_size, void* d_ws, size_t ws_size,
                              hipStream_t stream)
{
  const void* x_ctx = d_in[0];
  const void* label = d_in[1];
  const void* x_tgt = d_in[2];
  const void* W1 = d_in[3];
  const void* b1 = d_in[4];
  const void* W2 = d_in[5];
  const void* b2 = d_in[6];
  const void* W3 = d_in[7];
  const void* b3 = d_in[8];
  const void* Wk = d_in[9];
  const void* bk = d_in[10];
  const void* Wv = d_in[11];
  const void* bv = d_in[12];
  const void* Wq = d_in[13];
  const void* bq = d_in[14];
  const void* Wo = d_in[15];
  const void* bo = d_in[16];
  const void* Wmu = d_in[17];
  const void* bmu = d_in[18];
  const void* proj = d_in[19];

  // Arena (floats), peak ~84 MB
  float* W = (float*)d_ws;
  const long F0 = 0, F1 = 4194304, F2 = 8388608;
  const long CTXT_F = (long)64 * 256 * FP / 2;   // 12,058,624 floats
  const long F3 = F2 + CTXT_F;
  bf16* kB = (bf16*)(W + F0);
  bf16* qB = (bf16*)(W + F0);
  bf16* rep = (bf16*)(W + F0);
  bf16* vT = (bf16*)(W + F1);
  bf16* merged = (bf16*)(W + F1);
  bf16* h1 = (bf16*)(W + F2);
  bf16* h2 = (bf16*)(W + F2 + 524288);
  bf16* cf = (bf16*)(W + F2 + 1048576);
  bf16* ctxT = (bf16*)(W + F2);
  long o = F3;
  auto alloc = [&](long n) { float* p = W + o; o += n; return p; };
  float* dgk = alloc(32768);
  float* dgq = alloc(32768);
  float* ksumE = alloc((long)64 * NBF);
  float* mpart = alloc(64 * 23);
  float* mk = alloc(64);
  float* Sv = alloc(64 * 256);
  float* ctxs = alloc(64 * 256);
  float* ktot = alloc(64);
  int* dtFlag = (int*)alloc(64);
  bf16* projB = (bf16*)alloc((long)FP * 256 / 2);
  (void)ws_size; (void)in_sizes; (void)n_in; (void)out_size;

  const dim3 B(256);
  detect_dtype<<<1, B, 0, stream>>>(x_ctx, dtFlag);
  conv_proj<<<FP, B, 0, stream>>>(proj, projB, dtFlag);
  // 1. task-encoder MLP (bf16 activations)
  gemm_mfma<<<dim3(4, 64, 1), B, 0, stream>>>(
      x_ctx, 2, W1, nullptr, h1, 1, 0, 0, 0, dtFlag, 4096, 256, 256, 0L, 1, 0L, 1, 0L);
  fixup_h1<<<4096, B, 0, stream>>>(h1, label, W1, b1, dtFlag);
  gemm_mfma<<<dim3(4, 64, 1), B, 0, stream>>>(
      h1, 1, W2, b2, h2, 1, 2, 0, 0, dtFlag, 4096, 256, 256, 0L, 1, 0L, 1, 0L);
  gemm_mfma<<<dim3(4, 64, 1), B, 0, stream>>>(
      h2, 1, W3, b3, cf, 1, 2, 0, 0, dtFlag, 4096, 256, 256, 0L, 1, 0L, 1, 0L);
  // 2. k projection (natural), v projection (transposed -> vT)
  gemm_mfma<<<dim3(4, 8, 64), B, 0, stream>>>(
      x_ctx, 2, Wk, bk, kB, 1, 1, 0, 0, dtFlag, 512, 256, 256, (long)512 * 256, H_, 65536L, H_, 256L);
  gemm_mfma<<<dim3(4, 8, 64), B, 0, stream>>>(
      cf, 1, Wv, bv, vT, 1, 1, 0, 1, dtFlag, 512, 256, 256, (long)512 * 256, H_, 65536L, H_, 256L);
  // 3. key side (MFMA v2, FT=64, XCD-swizzled grid)
  diag_kernel<<<32768, 64, 0, stream>>>(kB, dgk);
  key_fused_mfma<<<dim3(64, 23), B, 0, stream>>>(kB, vT, projB, dgk, ksumE, ctxT, mpart);
  mk_reduce<<<64, 64, 0, stream>>>(mpart, mk);
  sv_kernel_T<<<64, B, 0, stream>>>(vT, Sv);
  ctx_finT<<<dim3(256, 64), B, 0, stream>>>(ctxT, Sv, mk);
  ksum_fin<<<64, B, 0, stream>>>(ksumE, mk, ktot);
  ctxsumT_k<<<64, B, 0, stream>>>(ctxT, ctxs);
  // 4. q projection + diag
  gemm_mfma<<<dim3(4, 8, 64), B, 0, stream>>>(
      x_tgt, 2, Wq, bq, qB, 1, 1, 0, 0, dtFlag, 512, 256, 256, (long)512 * 256, H_, 65536L, H_, 256L);
  diag_kernel<<<32768, 64, 0, stream>>>(qB, dgq);
  // 5. query side (MFMA, XCD-swizzled grid) -> merged [t][n][h][e]
  q_fused_mfma<<<dim3(64, 16), B, 0, stream>>>(qB, projB, dgq, ctxT, ksumE, ctxs, ktot, merged);
  // 6. output projections (Wo rows permuted: k=h*256+e -> logical e*8+h)
  gemm_mfma<<<dim3(4, 64, 1), B, 0, stream>>>(
      merged, 1, Wo, bo, rep, 1, 1, 1, 0, dtFlag, 4096, 256, 2048, 0L, 1, 0L, 1, 0L);
  gemm_mfma<<<dim3(4, 64, 1), B, 0, stream>>>(
      rep, 1, Wmu, bmu, d_out, 2, 1, 0, 0, dtFlag, 4096, 256, 256, 0L, 1, 0L, 1, 0L);
}

// Round 10
// 631.049 us; speedup vs baseline: 7.3614x; 1.2183x over previous
//
#include <hip/hip_runtime.h>
#include <hip/hip_bf16.h>

typedef __hip_bfloat16 bf16;
typedef __attribute__((ext_vector_type(8))) short short8;
typedef __attribute__((ext_vector_type(4))) float f32x4;
typedef __attribute__((ext_vector_type(4))) unsigned short us4;
#define DEV __device__ __forceinline__

static constexpr int T_ = 8, NC = 512, NT = 512, D_ = 256, H_ = 8, NBF = 1419;
static constexpr int FT32 = 46;             // 46 f-tiles of 32 (padded 1472)
static constexpr float EPS_ = 1e-4f;
static constexpr float DN = 0.25f;          // D^-0.25
static constexpr float DIAG_SC = 0.03125f;  // 0.5 * DN^2

DEV float bf2f(unsigned short u) { return __uint_as_float(((unsigned)u) << 16); }
DEV float tofloat(bf16 x) { return __bfloat162float(x); }
DEV unsigned short f2bu(float x) { bf16 h = __float2bfloat16(x); return *(unsigned short*)&h; }

DEV float ldx(const void* p, long i, int isb) {
  if (isb) return bf2f(((const unsigned short*)p)[i]);
  return ((const float*)p)[i];
}
DEV void stx(void* p, long i, float v, int isb) {
  if (isb) ((bf16*)p)[i] = __float2bfloat16(v);
  else     ((float*)p)[i] = v;
}
DEV void unpack8(uint4 u, float* dst) {
  unsigned w[4] = {u.x, u.y, u.z, u.w};
#pragma unroll
  for (int i = 0; i < 4; i++) {
    dst[2 * i + 0] = __uint_as_float((w[i] & 0xffffu) << 16);
    dst[2 * i + 1] = __uint_as_float(w[i] & 0xffff0000u);
  }
}

// ------------------------------------------------------------------
// dtype probe (1 = bf16 inputs, 0 = fp32)
// ------------------------------------------------------------------
__global__ __launch_bounds__(256)
void detect_dtype(const void* __restrict__ x, int* __restrict__ flag)
{
  __shared__ int bad;
  if (threadIdx.x == 0) bad = 0;
  __syncthreads();
  int mybad = 0;
  for (int j = 0; j < 16; j++) {
    long i = 2L * (threadIdx.x + 256L * j);
    unsigned short u = ((const unsigned short*)x)[i];
    int e = (u >> 7) & 0xff, mant = u & 0x7f;
    bool b = (e == 0xff) || (e >= 141) || (e <= 93 && !(e == 0 && mant == 0));
    mybad += b ? 1 : 0;
  }
  atomicAdd(&bad, mybad);
  __syncthreads();
  if (threadIdx.x == 0) *flag = (bad > 1024) ? 0 : 1;
}

// proj -> bf16 [FT32*32][256], zero rows past NBF
__global__ __launch_bounds__(256)
void conv_proj(const void* __restrict__ proj, bf16* __restrict__ projB,
               const int* __restrict__ dtFlag)
{
  const int fl = *dtFlag;
  int f = blockIdx.x, t = threadIdx.x;
  float v = (f < NBF) ? ldx(proj, (long)f * 256 + t, fl) : 0.f;
  projB[(long)f * 256 + t] = __float2bfloat16(v);
}

// ------------------------------------------------------------------
// MFMA GEMM. cT=0: natural row-major. cT=2: MFMA-tiled store
//   C_tiled[(bz*(M/32) + m/32)*N*32 + n*32 + (m%31)] (for vQ).
// ------------------------------------------------------------------
__global__ __launch_bounds__(256)
void gemm_mfma(const void* __restrict__ A, int aMode,
               const void* __restrict__ B, const void* __restrict__ bias,
               void* __restrict__ C, int cMode, int epi, int bPerm, int cT,
               const int* __restrict__ dtFlag,
               int M, int N, int K, long sA, int divA, long sB, int modB, long sBias)
{
  __shared__ bf16 As[64 * 40];
  __shared__ bf16 Ws[64 * 40];
  const int fl = *dtFlag;
  const int aB = (aMode == 2) ? fl : aMode;
  const int cB = (cMode == 2) ? fl : cMode;
  const int t = threadIdx.x;
  const int bz = blockIdx.z;
  const long aOff = (long)(bz / divA) * sA;
  const long bOff = (long)(bz % modB) * sB;
  const long biasOff = (long)(bz % modB) * sBias;
  const long cOff = (long)bz * (long)M * N;
  const int m0 = blockIdx.y * 64, n0 = blockIdx.x * 64;
  const int w = t >> 6, l = t & 63, quad = l >> 4, ln = l & 15;
  const int am = t >> 2, ak8 = (t & 3) * 8;
  const int wk = t & 31, wg = t >> 5;
  f32x4 acc[4] = {};

  for (int k0 = 0; k0 < K; k0 += 32) {
    if (aB == 1) {
      const uint4* src = (const uint4*)((const bf16*)A + aOff + (long)(m0 + am) * K + k0 + ak8);
      *(uint4*)(&As[am * 40 + ak8]) = *src;
    } else {
      const float* src = (const float*)A + aOff + (long)(m0 + am) * K + k0 + ak8;
      unsigned short tmp[8];
#pragma unroll
      for (int i = 0; i < 8; i++) tmp[i] = f2bu(src[i]);
      *(uint4*)(&As[am * 40 + ak8]) = *(const uint4*)tmp;
    }
    {
      int k = k0 + wk;
      int krow = bPerm ? (((k & 255) << 3) | (k >> 8)) : k;
      if (fl == 1) {
        uint4 u = *(const uint4*)((const bf16*)B + bOff + (long)krow * N + n0 + wg * 8);
        const unsigned short* us = (const unsigned short*)&u;
#pragma unroll
        for (int j = 0; j < 8; j++) Ws[(wg * 8 + j) * 40 + wk] = *(const bf16*)&us[j];
      } else {
        const float* src = (const float*)B + bOff + (long)krow * N + n0 + wg * 8;
#pragma unroll
        for (int j = 0; j < 8; j++) {
          unsigned short u = f2bu(src[j]);
          Ws[(wg * 8 + j) * 40 + wk] = *(const bf16*)&u;
        }
      }
    }
    __syncthreads();
    short8 a = *(const short8*)(&As[(16 * w + ln) * 40 + quad * 8]);
#pragma unroll
    for (int i = 0; i < 4; i++) {
      short8 b = *(const short8*)(&Ws[(16 * i + ln) * 40 + quad * 8]);
      acc[i] = __builtin_amdgcn_mfma_f32_16x16x32_bf16(a, b, acc[i], 0, 0, 0);
    }
    __syncthreads();
  }

  if (cT == 2) {
    // tiled store (bf16 only): tile = m/32, off = m%32
    const int mm = m0 + 16 * w + quad * 4;
    const int tile = mm >> 5, off = mm & 31;
#pragma unroll
    for (int i = 0; i < 4; i++) {
      int n = n0 + 16 * i + ln;
      us4 cv;
#pragma unroll
      for (int r = 0; r < 4; r++) {
        float c = acc[i][r];
        if (epi >= 1) c += ldx(bias, biasOff + n, fl);
        if (epi == 2) c = fmaxf(c, 0.f);
        cv[r] = f2bu(c);
      }
      *(us4*)((bf16*)C + cOff + ((long)tile * N + n) * 32 + off) = cv;
    }
  } else {
#pragma unroll
    for (int i = 0; i < 4; i++) {
#pragma unroll
      for (int r = 0; r < 4; r++) {
        int m = m0 + 16 * w + quad * 4 + r;
        int n = n0 + 16 * i + ln;
        float c = acc[i][r];
        if (epi >= 1) c += ldx(bias, biasOff + n, fl);
        if (epi == 2) c = fmaxf(c, 0.f);
        stx(C, cOff + (long)m * N + n, c, cB);
      }
    }
  }
}

__global__ __launch_bounds__(256)
void fixup_h1(bf16* __restrict__ h1, const void* __restrict__ label,
              const void* __restrict__ W1, const void* __restrict__ b1,
              const int* __restrict__ dtFlag)
{
  const int fl = *dtFlag;
  int idx = blockIdx.x * 256 + threadIdx.x;
  int m = idx >> 8, n = idx & 255;
  float c = tofloat(h1[idx]) + ldx(b1, n, fl);
#pragma unroll
  for (int j = 0; j < 3; j++)
    c += ldx(label, m * 3 + j, fl) * ldx(W1, (256 + j) * 256 + n, fl);
  h1[idx] = __float2bfloat16(fmaxf(c, 0.f));
}

__global__ __launch_bounds__(64)
void diag_kernel(const bf16* __restrict__ X, float* __restrict__ diag)
{
  int r = blockIdx.x, lane = threadIdx.x;
  uint2 u = ((const uint2*)(X + (long)r * 256))[lane];
  float a = bf2f((unsigned short)(u.x & 0xffff)), b2 = bf2f((unsigned short)(u.x >> 16));
  float c = bf2f((unsigned short)(u.y & 0xffff)), d = bf2f((unsigned short)(u.y >> 16));
  float s = a * a + b2 * b2 + c * c + d * d;
#pragma unroll
  for (int off = 32; off > 0; off >>= 1) s += __shfl_down(s, off);
  if (lane == 0) diag[r] = DIAG_SC * s;
}

// ------------------------------------------------------------------
// Key-side fused v3: vQ tiled [bz][nt16][e256][n32] read DIRECTLY from
// global (coalesced 1KB/wave-load, L2-resident); no vS LDS. ctx written
// tiled: ctxQ[bz][ft32][e256][f32]. LDS ~22 KB.
// Grid (bz=64 X, ft=23 Y) XCD swizzle.
// ------------------------------------------------------------------
__global__ __launch_bounds__(256)
void key_fused_mfma(const bf16* __restrict__ k, const bf16* __restrict__ vQ,
                    const bf16* __restrict__ projB, const float* __restrict__ diagk,
                    float* __restrict__ ksumE, bf16* __restrict__ ctxQ,
                    float* __restrict__ mpart)
{
  __shared__ bf16 kS[32 * 264];
  __shared__ bf16 pS[64 * 40];
  __shared__ float dS[32];
  __shared__ float wredM[4];

  const int bz = blockIdx.x, ft = blockIdx.y, f0 = ft * 64;
  const int t = threadIdx.x;
  const int w = t >> 6, l = t & 63, quad = l >> 4, ln = l & 15;
  const int fmine = f0 + 16 * w + ln;
  const bool fv = fmine < NBF;

  short8 pf[8];
  {
    const bf16* prow = projB + (long)fmine * 256;
#pragma unroll
    for (int kc = 0; kc < 8; kc++)
      pf[kc] = *(const short8*)(prow + kc * 32 + quad * 8);
  }
  const bf16* kb = k + (long)bz * NC * 256;
  const bf16* vqb = vQ + (long)bz * 16 * 256 * 32;
  const float* db = diagk + bz * NC;

  f32x4 acc[4][4] = {};      // [fh][ei]: f = f0+16fh+quad*4+r, e = 64w+16ei+ln
  float ksumP = 0.f, mP = -1e30f;

  for (int n0 = 0; n0 < NC; n0 += 32) {
    const int nt = n0 >> 5;
    // direct coalesced vQ B-fragments (issued early, L2-resident)
    short8 bfr[4];
#pragma unroll
    for (int ei = 0; ei < 4; ei++) {
      int e = 64 * w + 16 * ei + ln;
      bfr[ei] = *(const short8*)(vqb + ((long)nt * 256 + e) * 32 + quad * 8);
    }
    {
      const int row = t >> 3, ch = (t & 7) * 32;
      const uint4* src = (const uint4*)(kb + (long)(n0 + row) * 256 + ch);
      uint4* dst = (uint4*)(&kS[row * 264 + ch]);
#pragma unroll
      for (int i = 0; i < 4; i++) dst[i] = src[i];
    }
    if (t < 32) dS[t] = db[n0 + t];
    __syncthreads();

    f32x4 dd[2][2] = {};
#pragma unroll
    for (int kc = 0; kc < 8; kc++) {
      const int hf = kc & 1;
#pragma unroll
      for (int mi = 0; mi < 2; mi++) {
        short8 a = *(const short8*)(&kS[(16 * mi + ln) * 264 + kc * 32 + quad * 8]);
        dd[mi][hf] = __builtin_amdgcn_mfma_f32_16x16x32_bf16(a, pf[kc], dd[mi][hf], 0, 0, 0);
      }
    }
#pragma unroll
    for (int mi = 0; mi < 2; mi++) {
      us4 ev;
#pragma unroll
      for (int r = 0; r < 4; r++) {
        float sc = DN * (dd[mi][0][r] + dd[mi][1][r]);
        float E = fv ? __expf(fminf(sc - dS[16 * mi + quad * 4 + r], 80.f)) : 0.f;
        unsigned short u = f2bu(E);
        ksumP += bf2f(u);
        if (fv) mP = fmaxf(mP, sc);
        ev[r] = u;
      }
      *(us4*)(&pS[(16 * w + ln) * 40 + 16 * mi + quad * 4]) = ev;
    }
    __syncthreads();

#pragma unroll
    for (int fh = 0; fh < 4; fh++) {
      short8 a = *(const short8*)(&pS[(16 * fh + ln) * 40 + quad * 8]);
#pragma unroll
      for (int ei = 0; ei < 4; ei++)
        acc[fh][ei] = __builtin_amdgcn_mfma_f32_16x16x32_bf16(a, bfr[ei], acc[fh][ei], 0, 0, 0);
    }
    __syncthreads();
  }

  // tiled ctxQ stores: [bz][ft32][e][f32]
#pragma unroll
  for (int fh = 0; fh < 4; fh++) {
    const int ft32 = 2 * ft + (fh >> 1);
    const int f32b = 16 * (fh & 1) + quad * 4;
#pragma unroll
    for (int ei = 0; ei < 4; ei++) {
      int e = 64 * w + 16 * ei + ln;
      us4 cv;
#pragma unroll
      for (int r = 0; r < 4; r++) cv[r] = f2bu(acc[fh][ei][r]);
      *(us4*)(&ctxQ[((long)(bz * FT32 + ft32) * 256 + e) * 32 + f32b]) = cv;
    }
  }

  float s = ksumP;
  s += __shfl_xor(s, 16); s += __shfl_xor(s, 32);
  if (quad == 0 && fv) ksumE[(long)bz * NBF + fmine] = s;
  float m = mP;
#pragma unroll
  for (int off = 1; off < 64; off <<= 1) m = fmaxf(m, __shfl_xor(m, off));
  if (l == 0) wredM[w] = m;
  __syncthreads();
  if (t == 0)
    mpart[bz * 23 + ft] = fmaxf(fmaxf(wredM[0], wredM[1]), fmaxf(wredM[2], wredM[3]));
}

__global__ __launch_bounds__(64)
void mk_reduce(const float* __restrict__ mpart, float* __restrict__ mk)
{
  int bz = blockIdx.x, l = threadIdx.x;
  float m = (l < 23) ? mpart[bz * 23 + l] : -1e30f;
#pragma unroll
  for (int off = 32; off > 0; off >>= 1) m = fmaxf(m, __shfl_down(m, off));
  if (l == 0) mk[bz] = m;
}

// Sv from tiled vQ: thread e sums 16 tiles x 32
__global__ __launch_bounds__(256)
void sv_kernel_Q(const bf16* __restrict__ vQ, float* __restrict__ Sv)
{
  int bz = blockIdx.x, e = threadIdx.x;
  float s = 0.f;
  for (int nt = 0; nt < 16; nt++) {
    const uint4* r4 = (const uint4*)(vQ + ((long)(bz * 16 + nt) * 256 + e) * 32);
#pragma unroll
    for (int i = 0; i < 4; i++) {
      float tmp[8];
      unpack8(r4[i], tmp);
#pragma unroll
      for (int j = 0; j < 8; j++) s += tmp[j];
    }
  }
  Sv[bz * 256 + e] = s;
}

// ctxQ finalize (tiled): f<NBF: x = emk*x + EPS*Sv[e] ; else 0
__global__ __launch_bounds__(256)
void ctx_finQ(bf16* __restrict__ ctxQ, const float* __restrict__ Sv,
              const float* __restrict__ mk)
{
  int ft32 = blockIdx.x, bz = blockIdx.y, e = threadIdx.x;
  float emk = __expf(-mk[bz]);
  float sve = EPS_ * Sv[bz * 256 + e];
  uint4* row = (uint4*)(ctxQ + ((long)(bz * FT32 + ft32) * 256 + e) * 32);
  int fbase = 32 * ft32;
#pragma unroll
  for (int cchunk = 0; cchunk < 4; cchunk++) {
    float tmp[8];
    unpack8(row[cchunk], tmp);
    unsigned short out[8];
#pragma unroll
    for (int j = 0; j < 8; j++) {
      int f = fbase + cchunk * 8 + j;
      float val = (f < NBF) ? (emk * tmp[j] + sve) : 0.f;
      out[j] = f2bu(val);
    }
    row[cchunk] = *(const uint4*)out;
  }
}

__global__ __launch_bounds__(256)
void ksum_fin(float* __restrict__ ksumE, const float* __restrict__ mk,
              float* __restrict__ ksumtot)
{
  __shared__ float red[4];
  int bz = blockIdx.x, t = threadIdx.x;
  float emk = __expf(-mk[bz]);
  float s = 0.f;
  for (int f = t; f < NBF; f += 256) {
    float kf = emk * ksumE[(long)bz * NBF + f] + (float)NC * EPS_;
    ksumE[(long)bz * NBF + f] = kf;
    s += kf;
  }
#pragma unroll
  for (int off = 32; off > 0; off >>= 1) s += __shfl_down(s, off);
  if ((t & 63) == 0) red[t >> 6] = s;
  __syncthreads();
  if (t == 0) ksumtot[bz] = red[0] + red[1] + red[2] + red[3];
}

// ctxsum over tiled ctxQ (padding already zeroed by ctx_finQ)
__global__ __launch_bounds__(256)
void ctxsumQ_k(const bf16* __restrict__ ctxQ, float* __restrict__ ctxsum)
{
  int bz = blockIdx.x, e = threadIdx.x;
  float s = 0.f;
  for (int ft32 = 0; ft32 < FT32; ft32++) {
    const uint4* r4 = (const uint4*)(ctxQ + ((long)(bz * FT32 + ft32) * 256 + e) * 32);
#pragma unroll
    for (int i = 0; i < 4; i++) {
      float tmp[8];
      unpack8(r4[i], tmp);
#pragma unroll
      for (int j = 0; j < 8; j++) s += tmp[j];
    }
  }
  ctxsum[bz * 256 + e] = s;
}

// ------------------------------------------------------------------
// Query-side fused v3: ctxQ B-fragments read DIRECTLY from global
// (coalesced, L2-resident); no ctxTs LDS. LDS ~38 KB.
// Grid (bz=64 X, nt=16 Y) XCD swizzle. merged [t][n][h][e].
// ------------------------------------------------------------------
__global__ __launch_bounds__(256)
void q_fused_mfma(const bf16* __restrict__ q, const bf16* __restrict__ projB,
                  const float* __restrict__ diagq, const bf16* __restrict__ ctxQ,
                  const float* __restrict__ ksum, const float* __restrict__ ctxsum,
                  const float* __restrict__ ksumtot, bf16* __restrict__ merged)
{
  __shared__ bf16 qS[32 * 264];
  __shared__ bf16 projS[32 * 264];
  __shared__ bf16 eS[32 * 40];
  __shared__ float ksumS[32];
  __shared__ float dS[32];
  __shared__ float csS[256];
  __shared__ float sS[32][2];
  __shared__ float mS[32][2];

  const int bz = blockIdx.x, nt = blockIdx.y, t = threadIdx.x;
  const int w = t >> 6, l = t & 63, quad = l >> 4, ln = l & 15;
  const int mi = w & 1, fi = w >> 1;
  const int tq = bz / H_, hh = bz % H_;
  const bf16* cqb = ctxQ + (long)bz * FT32 * 256 * 32;

  {
    const int row = t >> 3, ch = (t & 7) * 32;
    const uint4* src = (const uint4*)(q + ((long)bz * NT + nt * 32 + row) * 256 + ch);
    uint4* dst = (uint4*)(&qS[row * 264 + ch]);
#pragma unroll
    for (int i = 0; i < 4; i++) dst[i] = src[i];
  }
  if (t < 32) dS[t] = diagq[(long)bz * NT + nt * 32 + t];
  csS[t] = ctxsum[bz * 256 + t];

  f32x4 acc[2][4] = {};
  float sPart[4] = {0.f, 0.f, 0.f, 0.f};
  float mPart[4] = {0.f, 0.f, 0.f, 0.f};
  __syncthreads();

  for (int ft = 0; ft < FT32; ft++) {
    const int f0 = ft * 32;
    // direct coalesced ctxQ B-fragments (issued early, L2-resident)
    short8 cfr[4];
#pragma unroll
    for (int i = 0; i < 4; i++) {
      int e = 16 * (4 * w + i) + ln;
      cfr[i] = *(const short8*)(cqb + ((long)ft * 256 + e) * 32 + quad * 8);
    }
    {
      const int row = t >> 3, ch = (t & 7) * 32;
      const uint4* src = (const uint4*)(projB + (long)(f0 + row) * 256 + ch);
      uint4* dst = (uint4*)(&projS[row * 264 + ch]);
#pragma unroll
      for (int i = 0; i < 4; i++) dst[i] = src[i];
    }
    if (t < 32) ksumS[t] = (f0 + t < NBF) ? ksum[(long)bz * NBF + f0 + t] : 0.f;
    __syncthreads();

    f32x4 dd0 = {}, dd1 = {};
#pragma unroll
    for (int kc = 0; kc < 8; kc += 2) {
      short8 a0 = *(const short8*)(&qS[(16 * mi + ln) * 264 + kc * 32 + quad * 8]);
      short8 b0 = *(const short8*)(&projS[(16 * fi + ln) * 264 + kc * 32 + quad * 8]);
      dd0 = __builtin_amdgcn_mfma_f32_16x16x32_bf16(a0, b0, dd0, 0, 0, 0);
      short8 a1 = *(const short8*)(&qS[(16 * mi + ln) * 264 + (kc + 1) * 32 + quad * 8]);
      short8 b1 = *(const short8*)(&projS[(16 * fi + ln) * 264 + (kc + 1) * 32 + quad * 8]);
      dd1 = __builtin_amdgcn_mfma_f32_16x16x32_bf16(a1, b1, dd1, 0, 0, 0);
    }
    const bool fv = (f0 + 16 * fi + ln) < NBF;
    const float kv = ksumS[16 * fi + ln];
#pragma unroll
    for (int r = 0; r < 4; r++) {
      float E = fv ? __expf(fminf(DN * (dd0[r] + dd1[r]), 80.f)) : 0.f;
      bf16 h = __float2bfloat16(E);
      float Er = tofloat(h);
      eS[(16 * mi + quad * 4 + r) * 40 + 16 * fi + ln] = h;
      sPart[r] += Er * kv;
      mPart[r] = fmaxf(mPart[r], Er);
    }
    __syncthreads();

#pragma unroll
    for (int mh = 0; mh < 2; mh++) {
      short8 a = *(const short8*)(&eS[(16 * mh + ln) * 40 + quad * 8]);
#pragma unroll
      for (int i = 0; i < 4; i++)
        acc[mh][i] = __builtin_amdgcn_mfma_f32_16x16x32_bf16(a, cfr[i], acc[mh][i], 0, 0, 0);
    }
    __syncthreads();
  }

#pragma unroll
  for (int r = 0; r < 4; r++) {
    float s = sPart[r], m = mPart[r];
#pragma unroll
    for (int off = 1; off < 16; off <<= 1) {
      s += __shfl_xor(s, off);
      m = fmaxf(m, __shfl_xor(m, off));
    }
    if (ln == 0) {
      sS[16 * mi + quad * 4 + r][fi] = s;
      mS[16 * mi + quad * 4 + r][fi] = m;
    }
  }
  __syncthreads();

  const float ktotv = ksumtot[bz];
#pragma unroll
  for (int mh = 0; mh < 2; mh++) {
#pragma unroll
    for (int r = 0; r < 4; r++) {
      int row = 16 * mh + quad * 4 + r;
      float st = sS[row][0] + sS[row][1];
      float mt = fmaxf(fmaxf(mS[row][0], mS[row][1]), 1e-30f);
      float c = __expf(-dS[row]) / mt;
      float inv = 1.f / (c * st + EPS_ * ktotv);
#pragma unroll
      for (int i = 0; i < 4; i++) {
        int e = 16 * (4 * w + i) + ln;
        float val = (c * acc[mh][i][r] + EPS_ * csS[e]) * inv;
        merged[((long)tq * NT + nt * 32 + row) * 2048 + hh * 256 + e] =
            __float2bfloat16(val);
      }
    }
  }
}

// ------------------------------------------------------------------
extern "C" void kernel_launch(void* const* d_in, const int* in_sizes, int n_in,
                              void* d_out, int out_size, void* d_ws, size_t ws_size,
                              hipStream_t stream)
{
  const void* x_ctx = d_in[0];
  const void* label = d_in[1];
  const void* x_tgt = d_in[2];
  const void* W1 = d_in[3];
  const void* b1 = d_in[4];
  const void* W2 = d_in[5];
  const void* b2 = d_in[6];
  const void* W3 = d_in[7];
  const void* b3 = d_in[8];
  const void* Wk = d_in[9];
  const void* bk = d_in[10];
  const void* Wv = d_in[11];
  const void* bv = d_in[12];
  const void* Wq = d_in[13];
  const void* bq = d_in[14];
  const void* Wo = d_in[15];
  const void* bo = d_in[16];
  const void* Wmu = d_in[17];
  const void* bmu = d_in[18];
  const void* proj = d_in[19];

  // Arena (floats), peak ~84 MB
  float* W = (float*)d_ws;
  const long F0 = 0, F1 = 4194304, F2 = 8388608;
  const long CTXQ_F = (long)64 * FT32 * 256 * 32 / 2;   // 12,058,624 floats
  const long F3 = F2 + CTXQ_F;
  bf16* kB = (bf16*)(W + F0);
  bf16* qB = (bf16*)(W + F0);
  bf16* rep = (bf16*)(W + F0);
  bf16* vQ = (bf16*)(W + F1);
  bf16* merged = (bf16*)(W + F1);
  bf16* h1 = (bf16*)(W + F2);
  bf16* h2 = (bf16*)(W + F2 + 524288);
  bf16* cf = (bf16*)(W + F2 + 1048576);
  bf16* ctxQ = (bf16*)(W + F2);
  long o = F3;
  auto alloc = [&](long n) { float* p = W + o; o += n; return p; };
  float* dgk = alloc(32768);
  float* dgq = alloc(32768);
  float* ksumE = alloc((long)64 * NBF);
  float* mpart = alloc(64 * 23);
  float* mk = alloc(64);
  float* Sv = alloc(64 * 256);
  float* ctxs = alloc(64 * 256);
  float* ktot = alloc(64);
  int* dtFlag = (int*)alloc(64);
  bf16* projB = (bf16*)alloc((long)FT32 * 32 * 256 / 2);
  (void)ws_size; (void)in_sizes; (void)n_in; (void)out_size;

  const dim3 B(256);
  detect_dtype<<<1, B, 0, stream>>>(x_ctx, dtFlag);
  conv_proj<<<FT32 * 32, B, 0, stream>>>(proj, projB, dtFlag);
  // 1. task-encoder MLP (bf16 activations)
  gemm_mfma<<<dim3(4, 64, 1), B, 0, stream>>>(
      x_ctx, 2, W1, nullptr, h1, 1, 0, 0, 0, dtFlag, 4096, 256, 256, 0L, 1, 0L, 1, 0L);
  fixup_h1<<<4096, B, 0, stream>>>(h1, label, W1, b1, dtFlag);
  gemm_mfma<<<dim3(4, 64, 1), B, 0, stream>>>(
      h1, 1, W2, b2, h2, 1, 2, 0, 0, dtFlag, 4096, 256, 256, 0L, 1, 0L, 1, 0L);
  gemm_mfma<<<dim3(4, 64, 1), B, 0, stream>>>(
      h2, 1, W3, b3, cf, 1, 2, 0, 0, dtFlag, 4096, 256, 256, 0L, 1, 0L, 1, 0L);
  // 2. k projection (natural), v projection (tiled -> vQ)
  gemm_mfma<<<dim3(4, 8, 64), B, 0, stream>>>(
      x_ctx, 2, Wk, bk, kB, 1, 1, 0, 0, dtFlag, 512, 256, 256, (long)512 * 256, H_, 65536L, H_, 256L);
  gemm_mfma<<<dim3(4, 8, 64), B, 0, stream>>>(
      cf, 1, Wv, bv, vQ, 1, 1, 0, 2, dtFlag, 512, 256, 256, (long)512 * 256, H_, 65536L, H_, 256L);
  // 3. key side (MFMA v3)
  diag_kernel<<<32768, 64, 0, stream>>>(kB, dgk);
  key_fused_mfma<<<dim3(64, 23), B, 0, stream>>>(kB, vQ, projB, dgk, ksumE, ctxQ, mpart);
  mk_reduce<<<64, 64, 0, stream>>>(mpart, mk);
  sv_kernel_Q<<<64, B, 0, stream>>>(vQ, Sv);
  ctx_finQ<<<dim3(FT32, 64), B, 0, stream>>>(ctxQ, Sv, mk);
  ksum_fin<<<64, B, 0, stream>>>(ksumE, mk, ktot);
  ctxsumQ_k<<<64, B, 0, stream>>>(ctxQ, ctxs);
  // 4. q projection + diag
  gemm_mfma<<<dim3(4, 8, 64), B, 0, stream>>>(
      x_tgt, 2, Wq, bq, qB, 1, 1, 0, 0, dtFlag, 512, 256, 256, (long)512 * 256, H_, 65536L, H_, 256L);
  diag_kernel<<<32768, 64, 0, stream>>>(qB, dgq);
  // 5. query side (MFMA v3) -> merged [t][n][h][e]
  q_fused_mfma<<<dim3(64, 16), B, 0, stream>>>(qB, projB, dgq, ctxQ, ksumE, ctxs, ktot, merged);
  // 6. output projections (Wo rows permuted: k=h*256+e -> logical e*8+h)
  gemm_mfma<<<dim3(4, 64, 1), B, 0, stream>>>(
      merged, 1, Wo, bo, rep, 1, 1, 1, 0, dtFlag, 4096, 256, 2048, 0L, 1, 0L, 1, 0L);
  gemm_mfma<<<dim3(4, 64, 1), B, 0, stream>>>(
      rep, 1, Wmu, bmu, d_out, 2, 1, 0, 0, dtFlag, 4096, 256, 256, 0L, 1, 0L, 1, 0L);
}